// Round 15
// baseline (179.341 us; speedup 1.0000x reference)
//
#include <hip/hip_runtime.h>
#include <math.h>

#define NN 2048
#define BB 8
#define HH 2
#define NEG 0.2f
#define EPSL 1e-5f

typedef short bf16x8 __attribute__((ext_vector_type(8)));
typedef float f32x4 __attribute__((ext_vector_type(4)));

__device__ __forceinline__ float wave_reduce_sum(float v){
#pragma unroll
  for (int m = 32; m > 0; m >>= 1) v += __shfl_xor(v, m, 64);
  return v;
}

__device__ __forceinline__ unsigned short f2b(float f){
  union { float f; unsigned u; } v; v.f = f;
  unsigned r = v.u + 0x7FFFu + ((v.u >> 16) & 1u);
  return (unsigned short)(r >> 16);
}
__device__ __forceinline__ float b2f(unsigned short u){
  union { unsigned u; float f; } v; v.u = ((unsigned)u) << 16; return v.f;
}

// single block: LDS histogram count + exclusive scan -> row_start, cursor
__global__ void k_csr1(const int* __restrict__ dst, int E, int* row_start, int* cursor){
  __shared__ int cnt[2048];
  __shared__ int part[256];
  int tid = threadIdx.x;
  for(int i=tid;i<2048;i+=256) cnt[i]=0;
  __syncthreads();
  for(int i=tid;i<E;i+=256) atomicAdd(&cnt[dst[i]],1);
  __syncthreads();
  int loc[8]; int s = 0;
#pragma unroll
  for(int j=0;j<8;j++){ loc[j]=s; s += cnt[tid*8+j]; }
  part[tid]=s; __syncthreads();
  for(int off=1; off<256; off<<=1){
    int v = (tid>=off)? part[tid-off] : 0;
    __syncthreads();
    part[tid] += v;
    __syncthreads();
  }
  int excl = (tid==0)? 0 : part[tid-1];
#pragma unroll
  for(int j=0;j<8;j++){ int v=excl+loc[j]; row_start[tid*8+j]=v; cursor[tid*8+j]=v; }
  if(tid==255) row_start[2048]=excl+s;
}

__global__ void k_fill(const int* __restrict__ dst, const int* __restrict__ src,
                       int E, int* cursor, int* csrsrc){
  int i = blockIdx.x*256+threadIdx.x;
  if(i<E){ int p = atomicAdd(&cursor[dst[i]],1); csrsrc[p]=src[i]; }
}

// one-shot weight prep: bf16 images in final staging layouts
__global__ void k_prep(const float* __restrict__ W1, const float* __restrict__ al1, const float* __restrict__ ar1,
                       const float* __restrict__ W2, const float* __restrict__ al2, const float* __restrict__ ar2,
                       const float* __restrict__ tc1w, const float* __restrict__ tc2w,
                       const float* __restrict__ fcw,
                       unsigned short* wf1, unsigned short* wf2,
                       unsigned short* wc1, unsigned short* wc2,
                       unsigned short* wfc){
  int blk = blockIdx.x; int tid = threadIdx.x;
  if(blk==0){ for(int i=tid;i<8192;i+=256){ int k=i>>7, co=i&127; wf1[co*72+k]=f2b(W1[i]); } }
  else if(blk==1){ for(int i=tid;i<8192;i+=256){ int k=i>>7, co=i&127; wf2[co*72+k]=f2b(W2[i]); } }
  else if(blk==2){
    int k=tid>>2, q=tid&3, h=q&1;
    { const float* av=(q>>1)?ar1:al1; float s=0.f;
      for(int c=0;c<64;c++) s+=W1[k*128+h*64+c]*av[h*64+c];
      wf1[(128+q)*72+k]=f2b(s); }
    { const float* av=(q>>1)?ar2:al2; float s=0.f;
      for(int c=0;c<64;c++) s+=W2[k*128+h*64+c]*av[h*64+c];
      wf2[(128+q)*72+k]=f2b(s); }
  }
  else if(blk==3){
    for(int co=0;co<64;co++)
      for(int kap=tid;kap<320;kap+=256){
        int kt=kap>>6, ci=kap&63;
        wc1[co*320+kap]=f2b(tc1w[(co*64+ci)*5+kt]);
      }
  }
  else if(blk==4){ for(int i=tid;i<4096;i+=256) wc2[i]=f2b(tc2w[i]); }
  else {
    for(int i=tid;i<12288;i+=256){
      int o=i/768, f=i%768;
      wfc[i] = (o<12)? f2b(fcw[o*768+f]) : (unsigned short)0;
    }
  }
}

// prep layer-1 gather image: x fp32 [b][n][t][c] -> xg1 [n][t*8+b][c] bf16 (node-major)
// + el1/er1 [n][(t*8+b)*2+h] via thin MFMA with folded wlr (wf rows 128..131).
__global__ __launch_bounds__(256) void k_prepx1(
  const float* __restrict__ x, const unsigned short* __restrict__ wf,
  unsigned short* __restrict__ xg, float* __restrict__ el, float* __restrict__ er)
{
  __shared__ __align__(16) unsigned short xs[64*72];
  int tid = threadIdx.x; int r0 = blockIdx.x*64;
  for(int idx=tid; idx<1024; idx+=256){
    int rl=idx>>4, c4=(idx&15)*4;
    int row=r0+rl; int n_=row>>5, rb=row&31, t=rb>>3, b=rb&7;
    float4 v = *(const float4*)&x[(((size_t)b*2048+n_)*4 + t)*64 + c4];
    unsigned p0 = (unsigned)f2b(v.x) | ((unsigned)f2b(v.y)<<16);
    unsigned p1 = (unsigned)f2b(v.z) | ((unsigned)f2b(v.w)<<16);
    uint2 u = make_uint2(p0,p1);
    *(uint2*)&xs[rl*72+c4] = u;
    *(uint2*)&xg[(size_t)row*64 + c4] = u;
  }
  __syncthreads();
  int wv=tid>>6, lane=tid&63, lhi=lane>>4, llo=lane&15;
  f32x4 accE = (f32x4){0.f,0.f,0.f,0.f};
#pragma unroll
  for(int s=0;s<2;s++){
    bf16x8 a = *(const bf16x8*)&xs[(wv*16+llo)*72 + s*32 + lhi*8];
    bf16x8 be = *(const bf16x8*)&wf[(128+llo)*72 + s*32 + lhi*8];
    accE = __builtin_amdgcn_mfma_f32_16x16x32_bf16(a, be, accE, 0,0,0);
  }
  if(llo<4){
#pragma unroll
    for(int i=0;i<4;i++){
      int row = r0 + wv*16 + lhi*4 + i; int n_=row>>5, rb=row&31;
      int idx = n_*64 + rb*2 + (llo&1);
      if(llo<2) el[idx]=accE[i]; else er[idx]=accE[i];
    }
  }
}

// prep layer-2 gather image: x1g [n][64][64] raw -> LN1 -> xg2 [n][64][64] bf16
// + el2/er2 [n][rb*2+h] via wlr2. One node per block; mu index g = b*8+t2 (rb=t2*8+b).
__global__ __launch_bounds__(256) void k_prepx2(
  const unsigned short* __restrict__ x1g, const float* __restrict__ mu,
  const float* __restrict__ inv, const float* __restrict__ lnw, const float* __restrict__ lnb,
  const unsigned short* __restrict__ wf,
  unsigned short* __restrict__ xg2, float* __restrict__ el, float* __restrict__ er)
{
  __shared__ __align__(16) unsigned short xs[64*72];
  int n = blockIdx.x; int tid = threadIdx.x;
  for(int idx=tid; idx<1024; idx+=256){
    int rl=idx>>4, c4=(idx&15)*4;
    int t2=rl>>3, b=rl&7; int g=b*8+t2;
    uint2 u = *(const uint2*)&x1g[((size_t)n*64 + rl)*64 + c4];
    float m_=mu[g], iv=inv[g];
    float4 w4 = *(const float4*)&lnw[n*64+c4];
    float4 b4 = *(const float4*)&lnb[n*64+c4];
    float v0=(b2f((unsigned short)(u.x&0xffff))-m_)*iv*w4.x+b4.x;
    float v1=(b2f((unsigned short)(u.x>>16))  -m_)*iv*w4.y+b4.y;
    float v2=(b2f((unsigned short)(u.y&0xffff))-m_)*iv*w4.z+b4.z;
    float v3=(b2f((unsigned short)(u.y>>16))  -m_)*iv*w4.w+b4.w;
    unsigned p0 = (unsigned)f2b(v0)|((unsigned)f2b(v1)<<16);
    unsigned p1 = (unsigned)f2b(v2)|((unsigned)f2b(v3)<<16);
    uint2 o = make_uint2(p0,p1);
    *(uint2*)&xs[rl*72+c4] = o;
    *(uint2*)&xg2[((size_t)n*64+rl)*64 + c4] = o;
  }
  __syncthreads();
  int wv=tid>>6, lane=tid&63, lhi=lane>>4, llo=lane&15;
  f32x4 accE=(f32x4){0.f,0.f,0.f,0.f};
#pragma unroll
  for(int s=0;s<2;s++){
    bf16x8 a = *(const bf16x8*)&xs[(wv*16+llo)*72 + s*32 + lhi*8];
    bf16x8 be = *(const bf16x8*)&wf[(128+llo)*72 + s*32 + lhi*8];
    accE = __builtin_amdgcn_mfma_f32_16x16x32_bf16(a, be, accE, 0,0,0);
  }
  if(llo<4){
#pragma unroll
    for(int i=0;i<4;i++){
      int rb = wv*16 + lhi*4 + i;
      int idx = n*128 + rb*2 + (llo&1);
      if(llo<2) el[idx]=accE[i]; else er[idx]=accE[i];
    }
  }
}

// Fused GAT aggregate: gather INPUT x (64 ch) with per-(row,h) exp weights (linearity:
// out = W*(sum a_j x_j)), normalize, per-block MFMA with W (both heads), bias+relu,
// write output + LN partials. IR = input rows per node (32 layer1, 64 layer2).
template<int IR>
__global__ __launch_bounds__(256) void k_gat_fused(
  const unsigned short* __restrict__ xg, const float* __restrict__ el,
  const float* __restrict__ er, const int* __restrict__ row_start,
  const int* __restrict__ csrsrc, const unsigned short* __restrict__ wf,
  const float* __restrict__ bias, unsigned short* __restrict__ out,
  float2* __restrict__ pg)
{
  constexpr int TPR = 256/IR;     // threads per row (8 or 4)
  constexpr int CPL = 64/TPR;     // channels per lane (8 or 16)
  constexpr int NU  = CPL/8;      // uint4 per lane (1 or 2)
  constexpr int RT2 = IR/32;      // row tiles per wave (1 or 2)
  __shared__ __align__(16) unsigned short aggl[2][IR][72];
  int n = blockIdx.x; int tid = threadIdx.x;
  int beg = row_start[n]; int deg = row_start[n+1]-beg;
  int wv = tid>>6, lane = tid&63, lhi = lane>>4, llo = lane&15;
  int hW = wv>>1;

  // this wave's W_h panel (B-frags), L2-resident prepped image [co][72]
  bf16x8 Bf[4][2];
#pragma unroll
  for(int ct=0;ct<4;ct++)
#pragma unroll
    for(int s=0;s<2;s++)
      Bf[ct][s] = *(const bf16x8*)&wf[(hW*64+ct*16+llo)*72 + s*32 + lhi*8];

  // gather phase: thread owns (row r, channel slice), both heads' weights
  int r = tid/TPR; int dbase = (tid%TPR)*CPL;
  float2 ern = *(const float2*)&er[(size_t)n*(2*IR) + r*2];
  float acc0[CPL], acc1[CPL];
#pragma unroll
  for(int i=0;i<CPL;i++){ acc0[i]=0.f; acc1[i]=0.f; }
  float ss0=0.f, ss1=0.f;
  const unsigned short* xb = xg + (size_t)r*64 + dbase;

  int sn = csrsrc[beg];
  float2 elv = *(const float2*)&el[(size_t)sn*(2*IR) + r*2];
  uint4 cur[NU];
  {
    const unsigned short* fp = xb + (size_t)sn*(IR*64);
#pragma unroll
    for(int u=0;u<NU;u++) cur[u] = *(const uint4*)(fp + u*8);
  }
  for(int j=0;j<deg;j++){
    float2 elv2 = make_float2(0.f,0.f); uint4 nxt[NU];
    if(j+1<deg){
      int sn2 = csrsrc[beg+j+1];
      elv2 = *(const float2*)&el[(size_t)sn2*(2*IR) + r*2];
      const unsigned short* fp2 = xb + (size_t)sn2*(IR*64);
#pragma unroll
      for(int u=0;u<NU;u++) nxt[u] = *(const uint4*)(fp2 + u*8);
    }
    float e0 = elv.x + ern.x; e0 = e0>0.f? e0 : NEG*e0;
    float e1 = elv.y + ern.y; e1 = e1>0.f? e1 : NEG*e1;
    float w0 = __expf(e0), w1 = __expf(e1);
    ss0 += w0; ss1 += w1;
    const unsigned short* pu = (const unsigned short*)cur;
#pragma unroll
    for(int i=0;i<CPL;i++){ float xv = b2f(pu[i]); acc0[i] += w0*xv; acc1[i] += w1*xv; }
    if(j+1<deg){
      elv = elv2;
#pragma unroll
      for(int u=0;u<NU;u++) cur[u] = nxt[u];
    }
  }
  float is0 = 1.f/ss0, is1 = 1.f/ss1;
#pragma unroll
  for(int i=0;i<CPL;i++){
    aggl[0][r][dbase+i] = f2b(acc0[i]*is0);
    aggl[1][r][dbase+i] = f2b(acc1[i]*is1);
  }
  __syncthreads();

  // per-block GEMM: out rows (r, hW) = agg_h[r] * W_h
  f32x4 acc[RT2][4];
#pragma unroll
  for(int rt=0;rt<RT2;rt++)
#pragma unroll
    for(int ct=0;ct<4;ct++) acc[rt][ct]=(f32x4){0.f,0.f,0.f,0.f};
  int rbase = (wv&1)*(IR/2);
#pragma unroll
  for(int rt=0;rt<RT2;rt++){
#pragma unroll
    for(int s=0;s<2;s++){
      bf16x8 a = *(const bf16x8*)&aggl[hW][rbase+rt*16+llo][s*32+lhi*8];
#pragma unroll
      for(int ct=0;ct<4;ct++)
        acc[rt][ct] = __builtin_amdgcn_mfma_f32_16x16x32_bf16(a, Bf[ct][s], acc[rt][ct], 0,0,0);
    }
  }

#pragma unroll
  for(int rt=0;rt<RT2;rt++){
    float bb[4];
#pragma unroll
    for(int ct=0;ct<4;ct++) bb[ct] = bias[hW*64 + ct*16 + llo];
#pragma unroll
    for(int i=0;i<4;i++){
      int ro = rbase + rt*16 + lhi*4 + i;
      int t_new = (ro>>3)*2 + hW; int bq = ro&7;
      size_t off;
      if constexpr (IR==32) off = ((size_t)n*64 + t_new*8 + bq)*64;      // x1g node-major
      else                  off = (((size_t)bq*2048 + n)*16 + t_new)*64; // x2 conv layout
      float ps=0.f, pq=0.f;
#pragma unroll
      for(int ct=0;ct<4;ct++){
        float v = fmaxf(acc[rt][ct][i] + bb[ct], 0.f);
        out[off + ct*16 + llo] = f2b(v);
        ps += v; pq += v*v;
      }
#pragma unroll
      for(int mM=1;mM<=8;mM<<=1){ ps += __shfl_xor(ps,mM,64); pq += __shfl_xor(pq,mM,64); }
      if(llo==0) pg[(size_t)(ro*2+hW)*2048 + n] = make_float2(ps,pq);
    }
  }
}

// finalize LN stats. mode0: pg[r][2048], r=(t*8+b)*2+h; gout = b*TT2+t*2+h
// mode1: pr2[((b*2048+n)*12+to)*2 + s] (conv, 2 co-half partials)
__global__ void k_lnfin(const float2* __restrict__ p, float* __restrict__ mu, float* __restrict__ inv,
                        int mode, int TT2){
  int g = blockIdx.x; int tid = threadIdx.x;
  float s=0.f, q=0.f;
  if(mode==0){
    int base = g*2048;
    for(int i=tid;i<2048;i+=256){ float2 v = p[base + i]; s+=v.x; q+=v.y; }
  } else {
    int b = g/12; int to = g - b*12;
    for(int i=tid;i<4096;i+=256){
      int n_ = i>>1; int s2 = i&1;
      float2 v = p[((size_t)(b*2048+n_)*12 + to)*2 + s2];
      s+=v.x; q+=v.y;
    }
  }
  s = wave_reduce_sum(s); q = wave_reduce_sum(q);
  __shared__ float red[8];
  int wid=tid>>6, lane=tid&63;
  if(lane==0){ red[wid]=s; red[4+wid]=q; }
  __syncthreads();
  if(tid==0){
    float S=red[0]+red[1]+red[2]+red[3];
    float Q=red[4]+red[5]+red[6]+red[7];
    float cnt = 131072.f;
    float m = S/cnt; float var = Q/cnt - m*m;
    int gout;
    if(mode==0){ int h=g&1; int b=(g>>1)&7; int t=g>>4; gout = b*TT2 + t*2 + h; }
    else gout = g;
    mu[gout]=m; inv[gout]=rsqrtf(var+EPSL);
  }
}

// Temporal conv as MFMA GEMM. Wave = (row-half, co-half): each ds_read A-frag feeds
// 2 MFMAs (32 co in regs: 2xKSTEPS B-frags). Halves LDS-read traffic vs 16-co split.
template<int TIN, int TOUT, int KT, bool PSUM>
__global__ __launch_bounds__(256) void k_convT(
  const unsigned short* __restrict__ xin,
  const float* __restrict__ mu, const float* __restrict__ inv,
  const float* __restrict__ lnw, const float* __restrict__ lnb,
  const unsigned short* __restrict__ wcg,   // [64][KT*64] bf16
  const float* __restrict__ bias,
  unsigned short* __restrict__ y, float2* __restrict__ pr2)
{
  constexpr int K = KT*64;
  constexpr int KSTEPS = K/32;          // 10 (tc1) or 2 (tc2)
  constexpr int XPAD = 72;
  constexpr int XN = TIN*XPAD + 8;
  constexpr int NODES = 16;
  constexpr int HALF = NODES*TOUT/2;    // 96 rows per half
  constexpr int RT = HALF/16;           // 6 row-tiles per wave
  __shared__ __align__(16) unsigned short xs[NODES*XN];
  int tid = threadIdx.x;
  int bn0 = blockIdx.x*NODES;
  int r0 = bn0*TOUT;
  int wv_ = tid>>6, lane = tid&63, lhi = lane>>4, llo = lane&15;
  int hr = wv_&1, chf = wv_>>1;         // row half, co half

  // wave-private B-panels (32 co) in registers
  bf16x8 bB[2][KSTEPS];
#pragma unroll
  for(int ct=0;ct<2;ct++){
    const unsigned short* wrow = wcg + (chf*32+ct*16+llo)*K;
#pragma unroll
    for(int s=0;s<KSTEPS;s++) bB[ct][s] = *(const bf16x8*)(wrow + s*32 + lhi*8);
  }

  // stage X with LN: thread (nd, c4) covers t=0..TIN-1
  {
    int nd = tid>>4; int c4 = (tid&15)*4;
    int bn = bn0+nd; int b = bn0>>11; int n_ = bn&2047;
    float4 w4 = *(const float4*)&lnw[n_*64+c4];
    float4 b4 = *(const float4*)&lnb[n_*64+c4];
    const unsigned short* xp = xin + (size_t)bn*TIN*64 + c4;
    unsigned short* p0 = &xs[nd*XN + c4];
#pragma unroll
    for(int t=0;t<TIN;t++){
      uint2 u = *(const uint2*)(xp + t*64);
      float m_ = mu[b*TIN+t], iv = inv[b*TIN+t];
      float iw0 = iv*w4.x, iw1 = iv*w4.y, iw2 = iv*w4.z, iw3 = iv*w4.w;
      unsigned short* p = p0 + t*XPAD;
      p[0]=f2b((b2f((unsigned short)(u.x&0xffff))-m_)*iw0+b4.x);
      p[1]=f2b((b2f((unsigned short)(u.x>>16))  -m_)*iw1+b4.y);
      p[2]=f2b((b2f((unsigned short)(u.y&0xffff))-m_)*iw2+b4.z);
      p[3]=f2b((b2f((unsigned short)(u.y>>16))  -m_)*iw3+b4.w);
    }
  }
  __syncthreads();

  f32x4 acc[RT][2];
#pragma unroll
  for(int rt=0;rt<RT;rt++){ acc[rt][0]=(f32x4){0.f,0.f,0.f,0.f}; acc[rt][1]=(f32x4){0.f,0.f,0.f,0.f}; }

#pragma unroll
  for(int rt=0; rt<RT; rt++){
    int rr = hr*HALF + rt*16 + llo;
    int nd = rr/TOUT; int to = rr - nd*TOUT;
    const unsigned short* ap = &xs[nd*XN + to*XPAD];
#pragma unroll
    for(int s=0;s<KSTEPS;s++){
      int ktap = s>>1; int cib = ((s&1)<<5) + lhi*8;
      bf16x8 a = *(const bf16x8*)(ap + ktap*XPAD + cib);
      acc[rt][0] = __builtin_amdgcn_mfma_f32_16x16x32_bf16(a, bB[0][s], acc[rt][0], 0,0,0);
      acc[rt][1] = __builtin_amdgcn_mfma_f32_16x16x32_bf16(a, bB[1][s], acc[rt][1], 0,0,0);
    }
  }

  float bb0 = bias[chf*32 + llo], bb1 = bias[chf*32 + 16 + llo];
#pragma unroll
  for(int rt=0; rt<RT; rt++){
#pragma unroll
    for(int i=0;i<4;i++){
      int row = r0 + hr*HALF + rt*16 + lhi*4 + i;
      float v0 = acc[rt][0][i] + bb0;
      float v1 = acc[rt][1][i] + bb1;
      y[(size_t)row*64 + chf*32 + llo]      = f2b(v0);
      y[(size_t)row*64 + chf*32 + 16 + llo] = f2b(v1);
      if constexpr (PSUM){
        float s = v0+v1, q = v0*v0+v1*v1;
#pragma unroll
        for(int mM=1;mM<=8;mM<<=1){ s += __shfl_xor(s,mM,64); q += __shfl_xor(q,mM,64); }
        if(llo==0) pr2[(size_t)row*2 + chf] = make_float2(s,q);
      }
    }
  }
}

// final fc as MFMA GEMM. Block=(b,nh). M=64 (c, split 16/wave), N=12(pad16, o), K=768.
__global__ __launch_bounds__(256) void k_fcm(const unsigned short* __restrict__ xt2,
  const unsigned short* __restrict__ wfc, const float* __restrict__ fb, float* __restrict__ out)
{
  constexpr int APAD = 102;
  __shared__ unsigned short A[2][64*APAD];
  int tid = threadIdx.x;
  int b = blockIdx.x>>5, nh = blockIdx.x&31;
  int wv = tid>>6, lane = tid&63, lhi = lane>>4, llo = lane&15;

  bf16x8 Bp[24];
  {
    const unsigned short* wrow = wfc + llo*768 + lhi*8;
#pragma unroll
    for(int s=0;s<24;s++) Bp[s] = *(const bf16x8*)(wrow + s*32);
  }

  int it_col[3], it_c8[3];
#pragma unroll
  for(int j=0;j<3;j++){
    int idx = j*256 + tid;
    it_c8[j] = idx&7;
    int tau = (idx>>3)%12; int nl = idx/96;
    it_col[j] = nl*12 + tau;
  }
  const unsigned short* xbase = xt2 + (size_t)(b*2048 + nh*64)*768;

  uint4 r[3];
#pragma unroll
  for(int j=0;j<3;j++)
    r[j] = *(const uint4*)(xbase + (size_t)it_col[j]*64 + it_c8[j]*8);
#pragma unroll
  for(int j=0;j<3;j++){
    const unsigned short* pr = (const unsigned short*)&r[j];
#pragma unroll
    for(int i=0;i<8;i++) A[0][(it_c8[j]*8+i)*APAD + it_col[j]] = pr[i];
  }
  __syncthreads();

  f32x4 acc = (f32x4){0.f,0.f,0.f,0.f};
  for(int ch=0; ch<8; ch++){
    int cur = ch&1;
    if(ch<7){
      const unsigned short* nb = xbase + (size_t)(ch+1)*8*768;
#pragma unroll
      for(int j=0;j<3;j++)
        r[j] = *(const uint4*)(nb + (size_t)it_col[j]*64 + it_c8[j]*8);
    }
#pragma unroll
    for(int s=0;s<3;s++){
      bf16x8 a = *(const bf16x8*)&A[cur][(wv*16+llo)*APAD + s*32 + lhi*8];
      acc = __builtin_amdgcn_mfma_f32_16x16x32_bf16(a, Bp[ch*3+s], acc, 0,0,0);
    }
    if(ch<7){
#pragma unroll
      for(int j=0;j<3;j++){
        const unsigned short* pr = (const unsigned short*)&r[j];
#pragma unroll
        for(int i=0;i<8;i++) A[cur^1][(it_c8[j]*8+i)*APAD + it_col[j]] = pr[i];
      }
      __syncthreads();
    }
  }

  if(llo<12){
    float bbv = fb[llo];
#pragma unroll
    for(int i=0;i<4;i++){
      int c = wv*16 + lhi*4 + i;
      out[((size_t)b*2048 + c*32 + nh)*12 + llo] = acc[i] + bbv;
    }
  }
}

extern "C" void kernel_launch(void* const* d_in, const int* in_sizes, int n_in,
                              void* d_out, int out_size, void* d_ws, size_t ws_size,
                              hipStream_t stream) {
  (void)n_in; (void)out_size; (void)ws_size;
  const float* x    = (const float*)d_in[0];
  const int*   src  = (const int*)d_in[1];
  const int*   dst  = (const int*)d_in[2];
  const float* W1   = (const float*)d_in[3];
  const float* al1  = (const float*)d_in[4];
  const float* ar1  = (const float*)d_in[5];
  const float* b1   = (const float*)d_in[6];
  const float* W2   = (const float*)d_in[7];
  const float* al2  = (const float*)d_in[8];
  const float* ar2  = (const float*)d_in[9];
  const float* b2   = (const float*)d_in[10];
  const float* ln1w = (const float*)d_in[11];
  const float* ln1b = (const float*)d_in[12];
  const float* ln2w = (const float*)d_in[13];
  const float* ln2b = (const float*)d_in[14];
  const float* tc1w = (const float*)d_in[15];
  const float* tc1b = (const float*)d_in[16];
  const float* ln3w = (const float*)d_in[17];
  const float* ln3b = (const float*)d_in[18];
  const float* tc2w = (const float*)d_in[19];
  const float* tc2b = (const float*)d_in[20];
  const float* fcw  = (const float*)d_in[21];
  const float* fcb  = (const float*)d_in[22];
  int E = in_sizes[1];

  unsigned short* U = (unsigned short*)d_ws;
  unsigned short* xg1 = U + 0;             // [2048][32][64] = 4,194,304
  unsigned short* x1g = U + 4194304;       // [2048][64][64] = 8,388,608
  unsigned short* xg2 = U + 12582912;      // [2048][64][64] = 8,388,608
  unsigned short* x2  = U + 20971520;      // [16384][16][64] = 16,777,216
  unsigned short* xt1 = U + 0;             // 12,582,912 (xg1+x1g dead by conv1)
  unsigned short* xt2 = U + 12582912;      // 12,582,912 (xg2+x2-head dead by conv2)
  unsigned short* wf1 = U + 37748736;      // 10368
  unsigned short* wf2 = wf1 + 10368;       // 10368
  unsigned short* wc1 = wf2 + 10368;       // 20480
  unsigned short* wc2 = wc1 + 20480;       // 4096
  unsigned short* wfc = wc2 + 4096;        // 12288
  float* F = (float*)(wfc + 12288);
  float* el1 = F;                    // 131072
  float* er1 = el1 + 131072;         // 131072
  float* el2 = er1 + 131072;         // 262144
  float* er2 = el2 + 262144;         // 262144
  float2* pg1 = (float2*)(er2 + 262144);   // 64*2048
  float2* pg2 = pg1 + 131072;              // 128*2048
  float2* pr2 = pg2 + 262144;              // 196608*2 (region reserved 786432)
  float* mu1  = (float*)(pr2 + 786432);    // 64
  float* inv1 = mu1 + 64;
  float* mu2  = inv1 + 64;                 // 128
  float* inv2 = mu2 + 128;
  float* mu3  = inv2 + 128;                // 96
  float* inv3 = mu3 + 96;
  int* cursor = (int*)(inv3 + 96);
  int* rs     = cursor + 2048;       // 2049
  int* csrsrc = rs + 2049;           // E

  int eb = (E+255)/256;

  k_prep<<<6,256,0,stream>>>(W1,al1,ar1, W2,al2,ar2, tc1w, tc2w, fcw, wf1, wf2, wc1, wc2, wfc);
  k_csr1<<<1,256,0,stream>>>(dst, E, rs, cursor);
  k_fill<<<eb,256,0,stream>>>(dst, src, E, cursor, csrsrc);

  // GAT layer 1: prep gather image + el/er, then fused aggregate+GEMM
  k_prepx1<<<1024,256,0,stream>>>(x, wf1, xg1, el1, er1);
  k_gat_fused<32><<<2048,256,0,stream>>>(xg1, el1, er1, rs, csrsrc, wf1, b1, x1g, pg1);
  k_lnfin<<<64,256,0,stream>>>(pg1, mu1, inv1, 0, 8);

  // GAT layer 2: LN1 + gather image + el/er, then fused aggregate+GEMM
  k_prepx2<<<2048,256,0,stream>>>(x1g, mu1, inv1, ln1w, ln1b, wf2, xg2, el2, er2);
  k_gat_fused<64><<<2048,256,0,stream>>>(xg2, el2, er2, rs, csrsrc, wf2, b2, x2, pg2);
  k_lnfin<<<128,256,0,stream>>>(pg2, mu2, inv2, 0, 16);

  // tc1 (5-tap, 16->12), LN2 fused, emits LN3 partials (2 co-half slices)
  k_convT<16,12,5,true><<<1024,256,0,stream>>>(x2, mu2, inv2, ln2w, ln2b, wc1, tc1b, xt1, pr2);
  k_lnfin<<<96,256,0,stream>>>(pr2, mu3, inv3, 1, 0);

  // tc2 (1x1), LN3 fused
  k_convT<12,12,1,false><<<1024,256,0,stream>>>(xt1, mu3, inv3, ln3w, ln3b, wc2, tc2b, xt2, nullptr);

  // final fc (MFMA)
  k_fcm<<<256,256,0,stream>>>(xt2, wfc, fcb, (float*)d_out);
}

// Round 16
// 175.527 us; speedup vs baseline: 1.0217x; 1.0217x over previous
//
#include <hip/hip_runtime.h>
#include <math.h>

#define NN 2048
#define BB 8
#define HH 2
#define NEG 0.2f
#define EPSL 1e-5f

typedef short bf16x8 __attribute__((ext_vector_type(8)));
typedef float f32x4 __attribute__((ext_vector_type(4)));

__device__ __forceinline__ float wave_reduce_sum(float v){
#pragma unroll
  for (int m = 32; m > 0; m >>= 1) v += __shfl_xor(v, m, 64);
  return v;
}

__device__ __forceinline__ unsigned short f2b(float f){
  union { float f; unsigned u; } v; v.f = f;
  unsigned r = v.u + 0x7FFFu + ((v.u >> 16) & 1u);
  return (unsigned short)(r >> 16);
}
__device__ __forceinline__ float b2f(unsigned short u){
  union { unsigned u; float f; } v; v.u = ((unsigned)u) << 16; return v.f;
}

// ONE front-end kernel:
//  blk 0-5  : weight prep (bf16 images)
//  blk 6    : CSR build (count + scan + fill) entirely in one block's LDS
//  blk 7+   : prepx1 (x fp32 -> xg1 bf16 node-major + el1/er1), wlr1 computed in-block
__global__ __launch_bounds__(256) void k_setup(
  const int* __restrict__ dst, const int* __restrict__ src, int E,
  const float* __restrict__ W1, const float* __restrict__ al1, const float* __restrict__ ar1,
  const float* __restrict__ W2, const float* __restrict__ al2, const float* __restrict__ ar2,
  const float* __restrict__ tc1w, const float* __restrict__ tc2w, const float* __restrict__ fcw,
  const float* __restrict__ x,
  unsigned short* wf1, unsigned short* wf2,
  unsigned short* wc1, unsigned short* wc2, unsigned short* wfc,
  int* row_start, int* csrsrc,
  unsigned short* __restrict__ xg, float* __restrict__ el, float* __restrict__ er)
{
  int blk = blockIdx.x; int tid = threadIdx.x;
  if(blk==0){ for(int i=tid;i<8192;i+=256){ int k=i>>7, co=i&127; wf1[co*72+k]=f2b(W1[i]); } return; }
  if(blk==1){ for(int i=tid;i<8192;i+=256){ int k=i>>7, co=i&127; wf2[co*72+k]=f2b(W2[i]); } return; }
  if(blk==2){
    int k=tid>>2, q=tid&3, h=q&1;
    { const float* av=(q>>1)?ar1:al1; float s=0.f;
      for(int c=0;c<64;c++) s+=W1[k*128+h*64+c]*av[h*64+c];
      wf1[(128+q)*72+k]=f2b(s); }
    { const float* av=(q>>1)?ar2:al2; float s=0.f;
      for(int c=0;c<64;c++) s+=W2[k*128+h*64+c]*av[h*64+c];
      wf2[(128+q)*72+k]=f2b(s); }
    return;
  }
  if(blk==3){
    for(int co=0;co<64;co++)
      for(int kap=tid;kap<320;kap+=256){
        int kt=kap>>6, ci=kap&63;
        wc1[co*320+kap]=f2b(tc1w[(co*64+ci)*5+kt]);
      }
    return;
  }
  if(blk==4){ for(int i=tid;i<4096;i+=256) wc2[i]=f2b(tc2w[i]); return; }
  if(blk==5){
    for(int i=tid;i<12288;i+=256){
      int o=i/768, f=i%768;
      wfc[i] = (o<12)? f2b(fcw[o*768+f]) : (unsigned short)0;
    }
    return;
  }
  if(blk==6){
    // CSR: count -> scan -> fill, all in LDS
    __shared__ int cnt[2048];
    __shared__ int part[256];
    for(int i=tid;i<2048;i+=256) cnt[i]=0;
    __syncthreads();
    for(int i=tid;i<E;i+=256) atomicAdd(&cnt[dst[i]],1);
    __syncthreads();
    int loc[8]; int s=0;
#pragma unroll
    for(int j=0;j<8;j++){ loc[j]=s; s += cnt[tid*8+j]; }
    part[tid]=s; __syncthreads();
    for(int off=1; off<256; off<<=1){
      int v = (tid>=off)? part[tid-off] : 0;
      __syncthreads();
      part[tid] += v;
      __syncthreads();
    }
    int excl = (tid==0)? 0 : part[tid-1];
#pragma unroll
    for(int j=0;j<8;j++){ int v=excl+loc[j]; row_start[tid*8+j]=v; cnt[tid*8+j]=v; }
    if(tid==255) row_start[2048]=excl+s;
    __syncthreads();
    for(int i=tid;i<E;i+=256){
      int p = atomicAdd(&cnt[dst[i]],1);
      csrsrc[p]=src[i];
    }
    return;
  }

  // prepx1 role
  __shared__ __align__(16) unsigned short xs[64*72];
  __shared__ __align__(16) unsigned short wl[16*72];
  int r0 = (blk-7)*64;
  // in-block wlr1 fold (deterministic, identical across blocks)
  for(int i=tid;i<16*72;i+=256) wl[i]=0;
  __syncthreads();
  {
    int k=tid>>2, q=tid&3, h=q&1;
    const float* av=(q>>1)?ar1:al1; float s=0.f;
    for(int c=0;c<64;c++) s+=W1[k*128+h*64+c]*av[h*64+c];
    wl[q*72+k]=f2b(s);
  }
  for(int idx=tid; idx<1024; idx+=256){
    int rl=idx>>4, c4=(idx&15)*4;
    int row=r0+rl; int n_=row>>5, rb=row&31, t=rb>>3, b=rb&7;
    float4 v = *(const float4*)&x[(((size_t)b*2048+n_)*4 + t)*64 + c4];
    unsigned p0 = (unsigned)f2b(v.x) | ((unsigned)f2b(v.y)<<16);
    unsigned p1 = (unsigned)f2b(v.z) | ((unsigned)f2b(v.w)<<16);
    uint2 u = make_uint2(p0,p1);
    *(uint2*)&xs[rl*72+c4] = u;
    *(uint2*)&xg[(size_t)row*64 + c4] = u;
  }
  __syncthreads();
  int wv=tid>>6, lane=tid&63, lhi=lane>>4, llo=lane&15;
  f32x4 accE = (f32x4){0.f,0.f,0.f,0.f};
#pragma unroll
  for(int s=0;s<2;s++){
    bf16x8 a = *(const bf16x8*)&xs[(wv*16+llo)*72 + s*32 + lhi*8];
    bf16x8 be = *(const bf16x8*)&wl[llo*72 + s*32 + lhi*8];
    accE = __builtin_amdgcn_mfma_f32_16x16x32_bf16(a, be, accE, 0,0,0);
  }
  if(llo<4){
#pragma unroll
    for(int i=0;i<4;i++){
      int row = r0 + wv*16 + lhi*4 + i; int n_=row>>5, rb=row&31;
      int idx = n_*64 + rb*2 + (llo&1);
      if(llo<2) el[idx]=accE[i]; else er[idx]=accE[i];
    }
  }
}

// prep layer-2 gather image: x1g [n][64][64] raw -> LN1 -> xg2 [n][64][64] bf16
// + el2/er2 [n][rb*2+h] via wlr2. One node per block; mu index g = b*8+t2 (rb=t2*8+b).
__global__ __launch_bounds__(256) void k_prepx2(
  const unsigned short* __restrict__ x1g, const float* __restrict__ mu,
  const float* __restrict__ inv, const float* __restrict__ lnw, const float* __restrict__ lnb,
  const unsigned short* __restrict__ wf,
  unsigned short* __restrict__ xg2, float* __restrict__ el, float* __restrict__ er)
{
  __shared__ __align__(16) unsigned short xs[64*72];
  int n = blockIdx.x; int tid = threadIdx.x;
  for(int idx=tid; idx<1024; idx+=256){
    int rl=idx>>4, c4=(idx&15)*4;
    int t2=rl>>3, b=rl&7; int g=b*8+t2;
    uint2 u = *(const uint2*)&x1g[((size_t)n*64 + rl)*64 + c4];
    float m_=mu[g], iv=inv[g];
    float4 w4 = *(const float4*)&lnw[n*64+c4];
    float4 b4 = *(const float4*)&lnb[n*64+c4];
    float v0=(b2f((unsigned short)(u.x&0xffff))-m_)*iv*w4.x+b4.x;
    float v1=(b2f((unsigned short)(u.x>>16))  -m_)*iv*w4.y+b4.y;
    float v2=(b2f((unsigned short)(u.y&0xffff))-m_)*iv*w4.z+b4.z;
    float v3=(b2f((unsigned short)(u.y>>16))  -m_)*iv*w4.w+b4.w;
    unsigned p0 = (unsigned)f2b(v0)|((unsigned)f2b(v1)<<16);
    unsigned p1 = (unsigned)f2b(v2)|((unsigned)f2b(v3)<<16);
    uint2 o = make_uint2(p0,p1);
    *(uint2*)&xs[rl*72+c4] = o;
    *(uint2*)&xg2[((size_t)n*64+rl)*64 + c4] = o;
  }
  __syncthreads();
  int wv=tid>>6, lane=tid&63, lhi=lane>>4, llo=lane&15;
  f32x4 accE=(f32x4){0.f,0.f,0.f,0.f};
#pragma unroll
  for(int s=0;s<2;s++){
    bf16x8 a = *(const bf16x8*)&xs[(wv*16+llo)*72 + s*32 + lhi*8];
    bf16x8 be = *(const bf16x8*)&wf[(128+llo)*72 + s*32 + lhi*8];
    accE = __builtin_amdgcn_mfma_f32_16x16x32_bf16(a, be, accE, 0,0,0);
  }
  if(llo<4){
#pragma unroll
    for(int i=0;i<4;i++){
      int rb = wv*16 + lhi*4 + i;
      int idx = n*128 + rb*2 + (llo&1);
      if(llo<2) el[idx]=accE[i]; else er[idx]=accE[i];
    }
  }
}

// Fused GAT aggregate: gather INPUT x (64 ch) with per-(row,h) exp weights (linearity:
// out = W*(sum a_j x_j)), normalize, per-block MFMA with W (both heads), bias+relu,
// write output + LN partials. IR = input rows per node (32 layer1, 64 layer2).
template<int IR>
__global__ __launch_bounds__(256) void k_gat_fused(
  const unsigned short* __restrict__ xg, const float* __restrict__ el,
  const float* __restrict__ er, const int* __restrict__ row_start,
  const int* __restrict__ csrsrc, const unsigned short* __restrict__ wf,
  const float* __restrict__ bias, unsigned short* __restrict__ out,
  float2* __restrict__ pg)
{
  constexpr int TPR = 256/IR;     // threads per row (8 or 4)
  constexpr int CPL = 64/TPR;     // channels per lane (8 or 16)
  constexpr int NU  = CPL/8;      // uint4 per lane (1 or 2)
  constexpr int RT2 = IR/32;      // row tiles per wave (1 or 2)
  __shared__ __align__(16) unsigned short aggl[2][IR][72];
  int n = blockIdx.x; int tid = threadIdx.x;
  int beg = row_start[n]; int deg = row_start[n+1]-beg;
  int wv = tid>>6, lane = tid&63, lhi = lane>>4, llo = lane&15;
  int hW = wv>>1;

  // this wave's W_h panel (B-frags), L2-resident prepped image [co][72]
  bf16x8 Bf[4][2];
#pragma unroll
  for(int ct=0;ct<4;ct++)
#pragma unroll
    for(int s=0;s<2;s++)
      Bf[ct][s] = *(const bf16x8*)&wf[(hW*64+ct*16+llo)*72 + s*32 + lhi*8];

  // gather phase: thread owns (row r, channel slice), both heads' weights
  int r = tid/TPR; int dbase = (tid%TPR)*CPL;
  float2 ern = *(const float2*)&er[(size_t)n*(2*IR) + r*2];
  float acc0[CPL], acc1[CPL];
#pragma unroll
  for(int i=0;i<CPL;i++){ acc0[i]=0.f; acc1[i]=0.f; }
  float ss0=0.f, ss1=0.f;
  const unsigned short* xb = xg + (size_t)r*64 + dbase;

  int sn = csrsrc[beg];
  float2 elv = *(const float2*)&el[(size_t)sn*(2*IR) + r*2];
  uint4 cur[NU];
  {
    const unsigned short* fp = xb + (size_t)sn*(IR*64);
#pragma unroll
    for(int u=0;u<NU;u++) cur[u] = *(const uint4*)(fp + u*8);
  }
  for(int j=0;j<deg;j++){
    float2 elv2 = make_float2(0.f,0.f); uint4 nxt[NU];
    if(j+1<deg){
      int sn2 = csrsrc[beg+j+1];
      elv2 = *(const float2*)&el[(size_t)sn2*(2*IR) + r*2];
      const unsigned short* fp2 = xb + (size_t)sn2*(IR*64);
#pragma unroll
      for(int u=0;u<NU;u++) nxt[u] = *(const uint4*)(fp2 + u*8);
    }
    float e0 = elv.x + ern.x; e0 = e0>0.f? e0 : NEG*e0;
    float e1 = elv.y + ern.y; e1 = e1>0.f? e1 : NEG*e1;
    float w0 = __expf(e0), w1 = __expf(e1);
    ss0 += w0; ss1 += w1;
    const unsigned short* pu = (const unsigned short*)cur;
#pragma unroll
    for(int i=0;i<CPL;i++){ float xv = b2f(pu[i]); acc0[i] += w0*xv; acc1[i] += w1*xv; }
    if(j+1<deg){
      elv = elv2;
#pragma unroll
      for(int u=0;u<NU;u++) cur[u] = nxt[u];
    }
  }
  float is0 = 1.f/ss0, is1 = 1.f/ss1;
#pragma unroll
  for(int i=0;i<CPL;i++){
    aggl[0][r][dbase+i] = f2b(acc0[i]*is0);
    aggl[1][r][dbase+i] = f2b(acc1[i]*is1);
  }
  __syncthreads();

  // per-block GEMM: out rows (r, hW) = agg_h[r] * W_h
  f32x4 acc[RT2][4];
#pragma unroll
  for(int rt=0;rt<RT2;rt++)
#pragma unroll
    for(int ct=0;ct<4;ct++) acc[rt][ct]=(f32x4){0.f,0.f,0.f,0.f};
  int rbase = (wv&1)*(IR/2);
#pragma unroll
  for(int rt=0;rt<RT2;rt++){
#pragma unroll
    for(int s=0;s<2;s++){
      bf16x8 a = *(const bf16x8*)&aggl[hW][rbase+rt*16+llo][s*32+lhi*8];
#pragma unroll
      for(int ct=0;ct<4;ct++)
        acc[rt][ct] = __builtin_amdgcn_mfma_f32_16x16x32_bf16(a, Bf[ct][s], acc[rt][ct], 0,0,0);
    }
  }

#pragma unroll
  for(int rt=0;rt<RT2;rt++){
    float bb[4];
#pragma unroll
    for(int ct=0;ct<4;ct++) bb[ct] = bias[hW*64 + ct*16 + llo];
#pragma unroll
    for(int i=0;i<4;i++){
      int ro = rbase + rt*16 + lhi*4 + i;
      int t_new = (ro>>3)*2 + hW; int bq = ro&7;
      size_t off;
      if constexpr (IR==32) off = ((size_t)n*64 + t_new*8 + bq)*64;      // x1g node-major
      else                  off = (((size_t)bq*2048 + n)*16 + t_new)*64; // x2 conv layout
      float ps=0.f, pq=0.f;
#pragma unroll
      for(int ct=0;ct<4;ct++){
        float v = fmaxf(acc[rt][ct][i] + bb[ct], 0.f);
        out[off + ct*16 + llo] = f2b(v);
        ps += v; pq += v*v;
      }
#pragma unroll
      for(int mM=1;mM<=8;mM<<=1){ ps += __shfl_xor(ps,mM,64); pq += __shfl_xor(pq,mM,64); }
      if(llo==0) pg[(size_t)(ro*2+hW)*2048 + n] = make_float2(ps,pq);
    }
  }
}

// finalize LN stats. mode0: pg[r][2048], r=(t*8+b)*2+h; gout = b*TT2+t*2+h
// mode1: pr4[((b*2048+n)*12+to)*4 + wv] (conv, co-sliced partials)
__global__ void k_lnfin(const float2* __restrict__ p, float* __restrict__ mu, float* __restrict__ inv,
                        int mode, int TT2){
  int g = blockIdx.x; int tid = threadIdx.x;
  float s=0.f, q=0.f;
  if(mode==0){
    int base = g*2048;
    for(int i=tid;i<2048;i+=256){ float2 v = p[base + i]; s+=v.x; q+=v.y; }
  } else {
    int b = g/12; int to = g - b*12;
    for(int i=tid;i<8192;i+=256){
      int n_ = i>>2; int wv = i&3;
      float2 v = p[((size_t)(b*2048+n_)*12 + to)*4 + wv];
      s+=v.x; q+=v.y;
    }
  }
  s = wave_reduce_sum(s); q = wave_reduce_sum(q);
  __shared__ float red[8];
  int wid=tid>>6, lane=tid&63;
  if(lane==0){ red[wid]=s; red[4+wid]=q; }
  __syncthreads();
  if(tid==0){
    float S=red[0]+red[1]+red[2]+red[3];
    float Q=red[4]+red[5]+red[6]+red[7];
    float cnt = 131072.f;
    float m = S/cnt; float var = Q/cnt - m*m;
    int gout;
    if(mode==0){ int h=g&1; int b=(g>>1)&7; int t=g>>4; gout = b*TT2 + t*2 + h; }
    else gout = g;
    mu[gout]=m; inv[gout]=rsqrtf(var+EPSL);
  }
}

// Temporal conv as MFMA GEMM (round-14 form). Co-split: wave w owns co [w*16, w*16+16);
// B-panel in regs. Staging: thread (nd, c4) owns all t.
template<int TIN, int TOUT, int KT, bool PSUM>
__global__ __launch_bounds__(256,4) void k_convT(
  const unsigned short* __restrict__ xin,
  const float* __restrict__ mu, const float* __restrict__ inv,
  const float* __restrict__ lnw, const float* __restrict__ lnb,
  const unsigned short* __restrict__ wcg,   // [64][KT*64] bf16
  const float* __restrict__ bias,
  unsigned short* __restrict__ y, float2* __restrict__ pr4)
{
  constexpr int K = KT*64;
  constexpr int KSTEPS = K/32;
  constexpr int XPAD = 72;
  constexpr int XN = TIN*XPAD + 8;
  constexpr int NODES = 16;
  constexpr int RT = NODES*TOUT/16;
  __shared__ __align__(16) unsigned short xs[NODES*XN];
  int tid = threadIdx.x;
  int bn0 = blockIdx.x*NODES;
  int r0 = bn0*TOUT;
  int wv_ = tid>>6, lane = tid&63, lhi = lane>>4, llo = lane&15;

  bf16x8 bB[KSTEPS];
  {
    const unsigned short* wrow = wcg + (wv_*16+llo)*K;
#pragma unroll
    for(int s=0;s<KSTEPS;s++) bB[s] = *(const bf16x8*)(wrow + s*32 + lhi*8);
  }

  {
    int nd = tid>>4; int c4 = (tid&15)*4;
    int bn = bn0+nd; int b = bn0>>11; int n_ = bn&2047;
    float4 w4 = *(const float4*)&lnw[n_*64+c4];
    float4 b4 = *(const float4*)&lnb[n_*64+c4];
    const unsigned short* xp = xin + (size_t)bn*TIN*64 + c4;
    unsigned short* p0 = &xs[nd*XN + c4];
#pragma unroll
    for(int t=0;t<TIN;t++){
      uint2 u = *(const uint2*)(xp + t*64);
      float m_ = mu[b*TIN+t], iv = inv[b*TIN+t];
      float iw0 = iv*w4.x, iw1 = iv*w4.y, iw2 = iv*w4.z, iw3 = iv*w4.w;
      unsigned short* p = p0 + t*XPAD;
      p[0]=f2b((b2f((unsigned short)(u.x&0xffff))-m_)*iw0+b4.x);
      p[1]=f2b((b2f((unsigned short)(u.x>>16))  -m_)*iw1+b4.y);
      p[2]=f2b((b2f((unsigned short)(u.y&0xffff))-m_)*iw2+b4.z);
      p[3]=f2b((b2f((unsigned short)(u.y>>16))  -m_)*iw3+b4.w);
    }
  }
  __syncthreads();

  f32x4 acc[RT];
#pragma unroll
  for(int rt=0;rt<RT;rt++) acc[rt] = (f32x4){0.f,0.f,0.f,0.f};

#pragma unroll
  for(int rt=0; rt<RT; rt++){
    int rr = rt*16 + llo;
    int nd = rr/TOUT; int to = rr - nd*TOUT;
    const unsigned short* ap = &xs[nd*XN + to*XPAD];
#pragma unroll
    for(int s=0;s<KSTEPS;s++){
      int ktap = s>>1; int cib = ((s&1)<<5) + lhi*8;
      bf16x8 a = *(const bf16x8*)(ap + ktap*XPAD + cib);
      acc[rt] = __builtin_amdgcn_mfma_f32_16x16x32_bf16(a, bB[s], acc[rt], 0,0,0);
    }
  }

  float bb = bias[wv_*16 + llo];
#pragma unroll
  for(int rt=0; rt<RT; rt++){
    float vs[4];
#pragma unroll
    for(int i=0;i<4;i++) vs[i] = acc[rt][i] + bb;
#pragma unroll
    for(int i=0;i<4;i++)
      y[(size_t)(r0 + rt*16 + lhi*4 + i)*64 + wv_*16 + llo] = f2b(vs[i]);
    if constexpr (PSUM){
#pragma unroll
      for(int i=0;i<4;i++){
        float s = vs[i], q = vs[i]*vs[i];
#pragma unroll
        for(int mM=1;mM<=8;mM<<=1){ s += __shfl_xor(s,mM,64); q += __shfl_xor(q,mM,64); }
        if(llo==0) pr4[(size_t)(r0 + rt*16 + lhi*4 + i)*4 + wv_] = make_float2(s,q);
      }
    }
  }
}

// final fc as MFMA GEMM. Block=(b,nh). M=64 (c, split 16/wave), N=12(pad16, o), K=768.
__global__ __launch_bounds__(256) void k_fcm(const unsigned short* __restrict__ xt2,
  const unsigned short* __restrict__ wfc, const float* __restrict__ fb, float* __restrict__ out)
{
  constexpr int APAD = 102;
  __shared__ unsigned short A[2][64*APAD];
  int tid = threadIdx.x;
  int b = blockIdx.x>>5, nh = blockIdx.x&31;
  int wv = tid>>6, lane = tid&63, lhi = lane>>4, llo = lane&15;

  bf16x8 Bp[24];
  {
    const unsigned short* wrow = wfc + llo*768 + lhi*8;
#pragma unroll
    for(int s=0;s<24;s++) Bp[s] = *(const bf16x8*)(wrow + s*32);
  }

  int it_col[3], it_c8[3];
#pragma unroll
  for(int j=0;j<3;j++){
    int idx = j*256 + tid;
    it_c8[j] = idx&7;
    int tau = (idx>>3)%12; int nl = idx/96;
    it_col[j] = nl*12 + tau;
  }
  const unsigned short* xbase = xt2 + (size_t)(b*2048 + nh*64)*768;

  uint4 r[3];
#pragma unroll
  for(int j=0;j<3;j++)
    r[j] = *(const uint4*)(xbase + (size_t)it_col[j]*64 + it_c8[j]*8);
#pragma unroll
  for(int j=0;j<3;j++){
    const unsigned short* pr = (const unsigned short*)&r[j];
#pragma unroll
    for(int i=0;i<8;i++) A[0][(it_c8[j]*8+i)*APAD + it_col[j]] = pr[i];
  }
  __syncthreads();

  f32x4 acc = (f32x4){0.f,0.f,0.f,0.f};
  for(int ch=0; ch<8; ch++){
    int cur = ch&1;
    if(ch<7){
      const unsigned short* nb = xbase + (size_t)(ch+1)*8*768;
#pragma unroll
      for(int j=0;j<3;j++)
        r[j] = *(const uint4*)(nb + (size_t)it_col[j]*64 + it_c8[j]*8);
    }
#pragma unroll
    for(int s=0;s<3;s++){
      bf16x8 a = *(const bf16x8*)&A[cur][(wv*16+llo)*APAD + s*32 + lhi*8];
      acc = __builtin_amdgcn_mfma_f32_16x16x32_bf16(a, Bp[ch*3+s], acc, 0,0,0);
    }
    if(ch<7){
#pragma unroll
      for(int j=0;j<3;j++){
        const unsigned short* pr = (const unsigned short*)&r[j];
#pragma unroll
        for(int i=0;i<8;i++) A[cur^1][(it_c8[j]*8+i)*APAD + it_col[j]] = pr[i];
      }
      __syncthreads();
    }
  }

  if(llo<12){
    float bbv = fb[llo];
#pragma unroll
    for(int i=0;i<4;i++){
      int c = wv*16 + lhi*4 + i;
      out[((size_t)b*2048 + c*32 + nh)*12 + llo] = acc[i] + bbv;
    }
  }
}

extern "C" void kernel_launch(void* const* d_in, const int* in_sizes, int n_in,
                              void* d_out, int out_size, void* d_ws, size_t ws_size,
                              hipStream_t stream) {
  (void)n_in; (void)out_size; (void)ws_size;
  const float* x    = (const float*)d_in[0];
  const int*   src  = (const int*)d_in[1];
  const int*   dst  = (const int*)d_in[2];
  const float* W1   = (const float*)d_in[3];
  const float* al1  = (const float*)d_in[4];
  const float* ar1  = (const float*)d_in[5];
  const float* b1   = (const float*)d_in[6];
  const float* W2   = (const float*)d_in[7];
  const float* al2  = (const float*)d_in[8];
  const float* ar2  = (const float*)d_in[9];
  const float* b2   = (const float*)d_in[10];
  const float* ln1w = (const float*)d_in[11];
  const float* ln1b = (const float*)d_in[12];
  const float* ln2w = (const float*)d_in[13];
  const float* ln2b = (const float*)d_in[14];
  const float* tc1w = (const float*)d_in[15];
  const float* tc1b = (const float*)d_in[16];
  const float* ln3w = (const float*)d_in[17];
  const float* ln3b = (const float*)d_in[18];
  const float* tc2w = (const float*)d_in[19];
  const float* tc2b = (const float*)d_in[20];
  const float* fcw  = (const float*)d_in[21];
  const float* fcb  = (const float*)d_in[22];
  int E = in_sizes[1];

  unsigned short* U = (unsigned short*)d_ws;
  unsigned short* xg1 = U + 0;             // [2048][32][64] = 4,194,304
  unsigned short* x1g = U + 4194304;       // [2048][64][64] = 8,388,608
  unsigned short* xg2 = U + 12582912;      // [2048][64][64] = 8,388,608
  unsigned short* x2  = U + 20971520;      // [16384][16][64] = 16,777,216
  unsigned short* xt1 = U + 0;             // 12,582,912 (xg1+x1g dead by conv1)
  unsigned short* xt2 = U + 12582912;      // 12,582,912 (xg2+x2-head dead by conv2)
  unsigned short* wf1 = U + 37748736;      // 10368
  unsigned short* wf2 = wf1 + 10368;       // 10368
  unsigned short* wc1 = wf2 + 10368;       // 20480
  unsigned short* wc2 = wc1 + 20480;       // 4096
  unsigned short* wfc = wc2 + 4096;        // 12288
  float* F = (float*)(wfc + 12288);
  float* el1 = F;                    // 131072
  float* er1 = el1 + 131072;         // 131072
  float* el2 = er1 + 131072;         // 262144
  float* er2 = el2 + 262144;         // 262144
  float2* pg1 = (float2*)(er2 + 262144);   // 64*2048
  float2* pg2 = pg1 + 131072;              // 128*2048
  float2* pr4 = pg2 + 262144;              // 196608*4
  float* mu1  = (float*)(pr4 + 786432);    // 64
  float* inv1 = mu1 + 64;
  float* mu2  = inv1 + 64;                 // 128
  float* inv2 = mu2 + 128;
  float* mu3  = inv2 + 128;                // 96
  float* inv3 = mu3 + 96;
  int* rs     = (int*)(inv3 + 96);   // 2049
  int* csrsrc = rs + 2049;           // E

  // front-end: weight prep + CSR + prepx1 in ONE kernel
  k_setup<<<1031,256,0,stream>>>(dst, src, E, W1,al1,ar1, W2,al2,ar2,
                                 tc1w, tc2w, fcw, x,
                                 wf1, wf2, wc1, wc2, wfc, rs, csrsrc,
                                 xg1, el1, er1);

  // GAT layer 1: fused aggregate+GEMM
  k_gat_fused<32><<<2048,256,0,stream>>>(xg1, el1, er1, rs, csrsrc, wf1, b1, x1g, pg1);
  k_lnfin<<<64,256,0,stream>>>(pg1, mu1, inv1, 0, 8);

  // GAT layer 2: LN1 + gather image + el/er, then fused aggregate+GEMM
  k_prepx2<<<2048,256,0,stream>>>(x1g, mu1, inv1, ln1w, ln1b, wf2, xg2, el2, er2);
  k_gat_fused<64><<<2048,256,0,stream>>>(xg2, el2, er2, rs, csrsrc, wf2, b2, x2, pg2);
  k_lnfin<<<128,256,0,stream>>>(pg2, mu2, inv2, 0, 16);

  // tc1 (5-tap, 16->12), LN2 fused, emits LN3 partials (co-sliced)
  k_convT<16,12,5,true><<<1024,256,0,stream>>>(x2, mu2, inv2, ln2w, ln2b, wc1, tc1b, xt1, pr4);
  k_lnfin<<<96,256,0,stream>>>(pr4, mu3, inv3, 1, 0);

  // tc2 (1x1), LN3 fused
  k_convT<12,12,1,false><<<1024,256,0,stream>>>(xt1, mu3, inv3, ln3w, ln3b, wc2, tc2b, xt2, nullptr);

  // final fc (MFMA)
  k_fcm<<<256,256,0,stream>>>(xt2, wfc, fcb, (float*)d_out);
}

// Round 17
// 173.046 us; speedup vs baseline: 1.0364x; 1.0143x over previous
//
#include <hip/hip_runtime.h>
#include <math.h>

#define NN 2048
#define BB 8
#define HH 2
#define NEG 0.2f
#define EPSL 1e-5f

typedef short bf16x8 __attribute__((ext_vector_type(8)));
typedef float f32x4 __attribute__((ext_vector_type(4)));

__device__ __forceinline__ float wave_reduce_sum(float v){
#pragma unroll
  for (int m = 32; m > 0; m >>= 1) v += __shfl_xor(v, m, 64);
  return v;
}

__device__ __forceinline__ unsigned short f2b(float f){
  union { float f; unsigned u; } v; v.f = f;
  unsigned r = v.u + 0x7FFFu + ((v.u >> 16) & 1u);
  return (unsigned short)(r >> 16);
}
__device__ __forceinline__ float b2f(unsigned short u){
  union { unsigned u; float f; } v; v.u = ((unsigned)u) << 16; return v.f;
}

// vectorized wlr fold: wlr[k][q] = sum_c W[k*128+h*64+c]*av[h*64+c], q=(ar?2:0)+h
__device__ __forceinline__ float fold_dot(const float* __restrict__ W,
                                          const float* __restrict__ av,
                                          int k, int h){
  float s = 0.f;
#pragma unroll
  for(int c4=0;c4<16;c4++){
    float4 w = *(const float4*)&W[k*128 + h*64 + c4*4];
    float4 a = *(const float4*)&av[h*64 + c4*4];
    s += w.x*a.x + w.y*a.y + w.z*a.z + w.w*a.w;
  }
  return s;
}

// ONE front-end kernel:
//  blk 0-5  : weight prep (bf16 images)
//  blk 6    : CSR build (count + scan + fill) entirely in one block's LDS
//  blk 7+   : prepx1 (x fp32 -> xg1 bf16 node-major + el1/er1), wlr1 computed in-block
__global__ __launch_bounds__(256) void k_setup(
  const int* __restrict__ dst, const int* __restrict__ src, int E,
  const float* __restrict__ W1, const float* __restrict__ al1, const float* __restrict__ ar1,
  const float* __restrict__ W2, const float* __restrict__ al2, const float* __restrict__ ar2,
  const float* __restrict__ tc1w, const float* __restrict__ tc2w, const float* __restrict__ fcw,
  const float* __restrict__ x,
  unsigned short* wf1, unsigned short* wf2,
  unsigned short* wc1, unsigned short* wc2, unsigned short* wfc,
  int* row_start, int* csrsrc,
  unsigned short* __restrict__ xg, float* __restrict__ el, float* __restrict__ er)
{
  int blk = blockIdx.x; int tid = threadIdx.x;
  if(blk==0){ for(int i=tid;i<8192;i+=256){ int k=i>>7, co=i&127; wf1[co*72+k]=f2b(W1[i]); } return; }
  if(blk==1){ for(int i=tid;i<8192;i+=256){ int k=i>>7, co=i&127; wf2[co*72+k]=f2b(W2[i]); } return; }
  if(blk==2){
    int k=tid>>2, q=tid&3, h=q&1;
    wf1[(128+q)*72+k] = f2b(fold_dot(W1, (q>>1)?ar1:al1, k, h));
    wf2[(128+q)*72+k] = f2b(fold_dot(W2, (q>>1)?ar2:al2, k, h));
    return;
  }
  if(blk==3){
    for(int co=0;co<64;co++)
      for(int kap=tid;kap<320;kap+=256){
        int kt=kap>>6, ci=kap&63;
        wc1[co*320+kap]=f2b(tc1w[(co*64+ci)*5+kt]);
      }
    return;
  }
  if(blk==4){ for(int i=tid;i<4096;i+=256) wc2[i]=f2b(tc2w[i]); return; }
  if(blk==5){
    for(int i=tid;i<12288;i+=256){
      int o=i/768, f=i%768;
      wfc[i] = (o<12)? f2b(fcw[o*768+f]) : (unsigned short)0;
    }
    return;
  }
  if(blk==6){
    // CSR: count -> scan -> fill, all in LDS
    __shared__ int cnt[2048];
    __shared__ int part[256];
    for(int i=tid;i<2048;i+=256) cnt[i]=0;
    __syncthreads();
    for(int i=tid;i<E;i+=256) atomicAdd(&cnt[dst[i]],1);
    __syncthreads();
    int loc[8]; int s=0;
#pragma unroll
    for(int j=0;j<8;j++){ loc[j]=s; s += cnt[tid*8+j]; }
    part[tid]=s; __syncthreads();
    for(int off=1; off<256; off<<=1){
      int v = (tid>=off)? part[tid-off] : 0;
      __syncthreads();
      part[tid] += v;
      __syncthreads();
    }
    int excl = (tid==0)? 0 : part[tid-1];
#pragma unroll
    for(int j=0;j<8;j++){ int v=excl+loc[j]; row_start[tid*8+j]=v; cnt[tid*8+j]=v; }
    if(tid==255) row_start[2048]=excl+s;
    __syncthreads();
    for(int i=tid;i<E;i+=256){
      int p = atomicAdd(&cnt[dst[i]],1);
      csrsrc[p]=src[i];
    }
    return;
  }

  // prepx1 role
  __shared__ __align__(16) unsigned short xs[64*72];
  __shared__ __align__(16) unsigned short wl[16*72];
  int r0 = (blk-7)*64;
  // in-block wlr1 fold (vectorized float4; deterministic, identical across blocks)
  for(int i=tid;i<16*72;i+=256) wl[i]=0;
  __syncthreads();
  {
    int k=tid>>2, q=tid&3, h=q&1;
    wl[q*72+k] = f2b(fold_dot(W1, (q>>1)?ar1:al1, k, h));
  }
  for(int idx=tid; idx<1024; idx+=256){
    int rl=idx>>4, c4=(idx&15)*4;
    int row=r0+rl; int n_=row>>5, rb=row&31, t=rb>>3, b=rb&7;
    float4 v = *(const float4*)&x[(((size_t)b*2048+n_)*4 + t)*64 + c4];
    unsigned p0 = (unsigned)f2b(v.x) | ((unsigned)f2b(v.y)<<16);
    unsigned p1 = (unsigned)f2b(v.z) | ((unsigned)f2b(v.w)<<16);
    uint2 u = make_uint2(p0,p1);
    *(uint2*)&xs[rl*72+c4] = u;
    *(uint2*)&xg[(size_t)row*64 + c4] = u;
  }
  __syncthreads();
  int wv=tid>>6, lane=tid&63, lhi=lane>>4, llo=lane&15;
  f32x4 accE = (f32x4){0.f,0.f,0.f,0.f};
#pragma unroll
  for(int s=0;s<2;s++){
    bf16x8 a = *(const bf16x8*)&xs[(wv*16+llo)*72 + s*32 + lhi*8];
    bf16x8 be = *(const bf16x8*)&wl[llo*72 + s*32 + lhi*8];
    accE = __builtin_amdgcn_mfma_f32_16x16x32_bf16(a, be, accE, 0,0,0);
  }
  if(llo<4){
#pragma unroll
    for(int i=0;i<4;i++){
      int row = r0 + wv*16 + lhi*4 + i; int n_=row>>5, rb=row&31;
      int idx = n_*64 + rb*2 + (llo&1);
      if(llo<2) el[idx]=accE[i]; else er[idx]=accE[i];
    }
  }
}

// prep layer-2 gather image: x1g [n][64][64] raw -> LN1 -> xg2 [n][64][64] bf16
// + el2/er2 [n][rb*2+h] via wlr2. One node per block; mu index g = b*8+t2 (rb=t2*8+b).
__global__ __launch_bounds__(256) void k_prepx2(
  const unsigned short* __restrict__ x1g, const float* __restrict__ mu,
  const float* __restrict__ inv, const float* __restrict__ lnw, const float* __restrict__ lnb,
  const unsigned short* __restrict__ wf,
  unsigned short* __restrict__ xg2, float* __restrict__ el, float* __restrict__ er)
{
  __shared__ __align__(16) unsigned short xs[64*72];
  int n = blockIdx.x; int tid = threadIdx.x;
  for(int idx=tid; idx<1024; idx+=256){
    int rl=idx>>4, c4=(idx&15)*4;
    int t2=rl>>3, b=rl&7; int g=b*8+t2;
    uint2 u = *(const uint2*)&x1g[((size_t)n*64 + rl)*64 + c4];
    float m_=mu[g], iv=inv[g];
    float4 w4 = *(const float4*)&lnw[n*64+c4];
    float4 b4 = *(const float4*)&lnb[n*64+c4];
    float v0=(b2f((unsigned short)(u.x&0xffff))-m_)*iv*w4.x+b4.x;
    float v1=(b2f((unsigned short)(u.x>>16))  -m_)*iv*w4.y+b4.y;
    float v2=(b2f((unsigned short)(u.y&0xffff))-m_)*iv*w4.z+b4.z;
    float v3=(b2f((unsigned short)(u.y>>16))  -m_)*iv*w4.w+b4.w;
    unsigned p0 = (unsigned)f2b(v0)|((unsigned)f2b(v1)<<16);
    unsigned p1 = (unsigned)f2b(v2)|((unsigned)f2b(v3)<<16);
    uint2 o = make_uint2(p0,p1);
    *(uint2*)&xs[rl*72+c4] = o;
    *(uint2*)&xg2[((size_t)n*64+rl)*64 + c4] = o;
  }
  __syncthreads();
  int wv=tid>>6, lane=tid&63, lhi=lane>>4, llo=lane&15;
  f32x4 accE=(f32x4){0.f,0.f,0.f,0.f};
#pragma unroll
  for(int s=0;s<2;s++){
    bf16x8 a = *(const bf16x8*)&xs[(wv*16+llo)*72 + s*32 + lhi*8];
    bf16x8 be = *(const bf16x8*)&wf[(128+llo)*72 + s*32 + lhi*8];
    accE = __builtin_amdgcn_mfma_f32_16x16x32_bf16(a, be, accE, 0,0,0);
  }
  if(llo<4){
#pragma unroll
    for(int i=0;i<4;i++){
      int rb = wv*16 + lhi*4 + i;
      int idx = n*128 + rb*2 + (llo&1);
      if(llo<2) el[idx]=accE[i]; else er[idx]=accE[i];
    }
  }
}

// Fused GAT aggregate: gather INPUT x (64 ch) with per-(row,h) exp weights (linearity:
// out = W*(sum a_j x_j)), normalize, per-block MFMA with W (both heads), bias+relu,
// write output + LN partials. IR = input rows per node (32 layer1, 64 layer2).
template<int IR>
__global__ __launch_bounds__(256) void k_gat_fused(
  const unsigned short* __restrict__ xg, const float* __restrict__ el,
  const float* __restrict__ er, const int* __restrict__ row_start,
  const int* __restrict__ csrsrc, const unsigned short* __restrict__ wf,
  const float* __restrict__ bias, unsigned short* __restrict__ out,
  float2* __restrict__ pg)
{
  constexpr int TPR = 256/IR;     // threads per row (8 or 4)
  constexpr int CPL = 64/TPR;     // channels per lane (8 or 16)
  constexpr int NU  = CPL/8;      // uint4 per lane (1 or 2)
  constexpr int RT2 = IR/32;      // row tiles per wave (1 or 2)
  __shared__ __align__(16) unsigned short aggl[2][IR][72];
  int n = blockIdx.x; int tid = threadIdx.x;
  int beg = row_start[n]; int deg = row_start[n+1]-beg;
  int wv = tid>>6, lane = tid&63, lhi = lane>>4, llo = lane&15;
  int hW = wv>>1;

  // this wave's W_h panel (B-frags), L2-resident prepped image [co][72]
  bf16x8 Bf[4][2];
#pragma unroll
  for(int ct=0;ct<4;ct++)
#pragma unroll
    for(int s=0;s<2;s++)
      Bf[ct][s] = *(const bf16x8*)&wf[(hW*64+ct*16+llo)*72 + s*32 + lhi*8];

  // gather phase: thread owns (row r, channel slice), both heads' weights
  int r = tid/TPR; int dbase = (tid%TPR)*CPL;
  float2 ern = *(const float2*)&er[(size_t)n*(2*IR) + r*2];
  float acc0[CPL], acc1[CPL];
#pragma unroll
  for(int i=0;i<CPL;i++){ acc0[i]=0.f; acc1[i]=0.f; }
  float ss0=0.f, ss1=0.f;
  const unsigned short* xb = xg + (size_t)r*64 + dbase;

  int sn = csrsrc[beg];
  float2 elv = *(const float2*)&el[(size_t)sn*(2*IR) + r*2];
  uint4 cur[NU];
  {
    const unsigned short* fp = xb + (size_t)sn*(IR*64);
#pragma unroll
    for(int u=0;u<NU;u++) cur[u] = *(const uint4*)(fp + u*8);
  }
  for(int j=0;j<deg;j++){
    float2 elv2 = make_float2(0.f,0.f); uint4 nxt[NU];
    if(j+1<deg){
      int sn2 = csrsrc[beg+j+1];
      elv2 = *(const float2*)&el[(size_t)sn2*(2*IR) + r*2];
      const unsigned short* fp2 = xb + (size_t)sn2*(IR*64);
#pragma unroll
      for(int u=0;u<NU;u++) nxt[u] = *(const uint4*)(fp2 + u*8);
    }
    float e0 = elv.x + ern.x; e0 = e0>0.f? e0 : NEG*e0;
    float e1 = elv.y + ern.y; e1 = e1>0.f? e1 : NEG*e1;
    float w0 = __expf(e0), w1 = __expf(e1);
    ss0 += w0; ss1 += w1;
    const unsigned short* pu = (const unsigned short*)cur;
#pragma unroll
    for(int i=0;i<CPL;i++){ float xv = b2f(pu[i]); acc0[i] += w0*xv; acc1[i] += w1*xv; }
    if(j+1<deg){
      elv = elv2;
#pragma unroll
      for(int u=0;u<NU;u++) cur[u] = nxt[u];
    }
  }
  float is0 = 1.f/ss0, is1 = 1.f/ss1;
#pragma unroll
  for(int i=0;i<CPL;i++){
    aggl[0][r][dbase+i] = f2b(acc0[i]*is0);
    aggl[1][r][dbase+i] = f2b(acc1[i]*is1);
  }
  __syncthreads();

  // per-block GEMM: out rows (r, hW) = agg_h[r] * W_h
  f32x4 acc[RT2][4];
#pragma unroll
  for(int rt=0;rt<RT2;rt++)
#pragma unroll
    for(int ct=0;ct<4;ct++) acc[rt][ct]=(f32x4){0.f,0.f,0.f,0.f};
  int rbase = (wv&1)*(IR/2);
#pragma unroll
  for(int rt=0;rt<RT2;rt++){
#pragma unroll
    for(int s=0;s<2;s++){
      bf16x8 a = *(const bf16x8*)&aggl[hW][rbase+rt*16+llo][s*32+lhi*8];
#pragma unroll
      for(int ct=0;ct<4;ct++)
        acc[rt][ct] = __builtin_amdgcn_mfma_f32_16x16x32_bf16(a, Bf[ct][s], acc[rt][ct], 0,0,0);
    }
  }

#pragma unroll
  for(int rt=0;rt<RT2;rt++){
    float bb[4];
#pragma unroll
    for(int ct=0;ct<4;ct++) bb[ct] = bias[hW*64 + ct*16 + llo];
#pragma unroll
    for(int i=0;i<4;i++){
      int ro = rbase + rt*16 + lhi*4 + i;
      int t_new = (ro>>3)*2 + hW; int bq = ro&7;
      size_t off;
      if constexpr (IR==32) off = ((size_t)n*64 + t_new*8 + bq)*64;      // x1g node-major
      else                  off = (((size_t)bq*2048 + n)*16 + t_new)*64; // x2 conv layout
      float ps=0.f, pq=0.f;
#pragma unroll
      for(int ct=0;ct<4;ct++){
        float v = fmaxf(acc[rt][ct][i] + bb[ct], 0.f);
        out[off + ct*16 + llo] = f2b(v);
        ps += v; pq += v*v;
      }
#pragma unroll
      for(int mM=1;mM<=8;mM<<=1){ ps += __shfl_xor(ps,mM,64); pq += __shfl_xor(pq,mM,64); }
      if(llo==0) pg[(size_t)(ro*2+hW)*2048 + n] = make_float2(ps,pq);
    }
  }
}

// finalize LN stats. mode0: pg[r][2048], r=(t*8+b)*2+h; gout = b*TT2+t*2+h
// mode1: pr4[((b*2048+n)*12+to)*4 + wv] (conv, co-sliced partials)
__global__ void k_lnfin(const float2* __restrict__ p, float* __restrict__ mu, float* __restrict__ inv,
                        int mode, int TT2){
  int g = blockIdx.x; int tid = threadIdx.x;
  float s=0.f, q=0.f;
  if(mode==0){
    int base = g*2048;
    for(int i=tid;i<2048;i+=256){ float2 v = p[base + i]; s+=v.x; q+=v.y; }
  } else {
    int b = g/12; int to = g - b*12;
    for(int i=tid;i<8192;i+=256){
      int n_ = i>>2; int wv = i&3;
      float2 v = p[((size_t)(b*2048+n_)*12 + to)*4 + wv];
      s+=v.x; q+=v.y;
    }
  }
  s = wave_reduce_sum(s); q = wave_reduce_sum(q);
  __shared__ float red[8];
  int wid=tid>>6, lane=tid&63;
  if(lane==0){ red[wid]=s; red[4+wid]=q; }
  __syncthreads();
  if(tid==0){
    float S=red[0]+red[1]+red[2]+red[3];
    float Q=red[4]+red[5]+red[6]+red[7];
    float cnt = 131072.f;
    float m = S/cnt; float var = Q/cnt - m*m;
    int gout;
    if(mode==0){ int h=g&1; int b=(g>>1)&7; int t=g>>4; gout = b*TT2 + t*2 + h; }
    else gout = g;
    mu[gout]=m; inv[gout]=rsqrtf(var+EPSL);
  }
}

// Temporal conv as MFMA GEMM (round-14 form). Co-split: wave w owns co [w*16, w*16+16);
// B-panel in regs. Staging: thread (nd, c4) owns all t.
template<int TIN, int TOUT, int KT, bool PSUM>
__global__ __launch_bounds__(256,4) void k_convT(
  const unsigned short* __restrict__ xin,
  const float* __restrict__ mu, const float* __restrict__ inv,
  const float* __restrict__ lnw, const float* __restrict__ lnb,
  const unsigned short* __restrict__ wcg,   // [64][KT*64] bf16
  const float* __restrict__ bias,
  unsigned short* __restrict__ y, float2* __restrict__ pr4)
{
  constexpr int K = KT*64;
  constexpr int KSTEPS = K/32;
  constexpr int XPAD = 72;
  constexpr int XN = TIN*XPAD + 8;
  constexpr int NODES = 16;
  constexpr int RT = NODES*TOUT/16;
  __shared__ __align__(16) unsigned short xs[NODES*XN];
  int tid = threadIdx.x;
  int bn0 = blockIdx.x*NODES;
  int r0 = bn0*TOUT;
  int wv_ = tid>>6, lane = tid&63, lhi = lane>>4, llo = lane&15;

  bf16x8 bB[KSTEPS];
  {
    const unsigned short* wrow = wcg + (wv_*16+llo)*K;
#pragma unroll
    for(int s=0;s<KSTEPS;s++) bB[s] = *(const bf16x8*)(wrow + s*32 + lhi*8);
  }

  {
    int nd = tid>>4; int c4 = (tid&15)*4;
    int bn = bn0+nd; int b = bn0>>11; int n_ = bn&2047;
    float4 w4 = *(const float4*)&lnw[n_*64+c4];
    float4 b4 = *(const float4*)&lnb[n_*64+c4];
    const unsigned short* xp = xin + (size_t)bn*TIN*64 + c4;
    unsigned short* p0 = &xs[nd*XN + c4];
#pragma unroll
    for(int t=0;t<TIN;t++){
      uint2 u = *(const uint2*)(xp + t*64);
      float m_ = mu[b*TIN+t], iv = inv[b*TIN+t];
      float iw0 = iv*w4.x, iw1 = iv*w4.y, iw2 = iv*w4.z, iw3 = iv*w4.w;
      unsigned short* p = p0 + t*XPAD;
      p[0]=f2b((b2f((unsigned short)(u.x&0xffff))-m_)*iw0+b4.x);
      p[1]=f2b((b2f((unsigned short)(u.x>>16))  -m_)*iw1+b4.y);
      p[2]=f2b((b2f((unsigned short)(u.y&0xffff))-m_)*iw2+b4.z);
      p[3]=f2b((b2f((unsigned short)(u.y>>16))  -m_)*iw3+b4.w);
    }
  }
  __syncthreads();

  f32x4 acc[RT];
#pragma unroll
  for(int rt=0;rt<RT;rt++) acc[rt] = (f32x4){0.f,0.f,0.f,0.f};

#pragma unroll
  for(int rt=0; rt<RT; rt++){
    int rr = rt*16 + llo;
    int nd = rr/TOUT; int to = rr - nd*TOUT;
    const unsigned short* ap = &xs[nd*XN + to*XPAD];
#pragma unroll
    for(int s=0;s<KSTEPS;s++){
      int ktap = s>>1; int cib = ((s&1)<<5) + lhi*8;
      bf16x8 a = *(const bf16x8*)(ap + ktap*XPAD + cib);
      acc[rt] = __builtin_amdgcn_mfma_f32_16x16x32_bf16(a, bB[s], acc[rt], 0,0,0);
    }
  }

  float bb = bias[wv_*16 + llo];
#pragma unroll
  for(int rt=0; rt<RT; rt++){
    float vs[4];
#pragma unroll
    for(int i=0;i<4;i++) vs[i] = acc[rt][i] + bb;
#pragma unroll
    for(int i=0;i<4;i++)
      y[(size_t)(r0 + rt*16 + lhi*4 + i)*64 + wv_*16 + llo] = f2b(vs[i]);
    if constexpr (PSUM){
#pragma unroll
      for(int i=0;i<4;i++){
        float s = vs[i], q = vs[i]*vs[i];
#pragma unroll
        for(int mM=1;mM<=8;mM<<=1){ s += __shfl_xor(s,mM,64); q += __shfl_xor(q,mM,64); }
        if(llo==0) pr4[(size_t)(r0 + rt*16 + lhi*4 + i)*4 + wv_] = make_float2(s,q);
      }
    }
  }
}

// final fc as MFMA GEMM. Block=(b,nh). M=64 (c, split 16/wave), N=12(pad16, o), K=768.
__global__ __launch_bounds__(256) void k_fcm(const unsigned short* __restrict__ xt2,
  const unsigned short* __restrict__ wfc, const float* __restrict__ fb, float* __restrict__ out)
{
  constexpr int APAD = 102;
  __shared__ unsigned short A[2][64*APAD];
  int tid = threadIdx.x;
  int b = blockIdx.x>>5, nh = blockIdx.x&31;
  int wv = tid>>6, lane = tid&63, lhi = lane>>4, llo = lane&15;

  bf16x8 Bp[24];
  {
    const unsigned short* wrow = wfc + llo*768 + lhi*8;
#pragma unroll
    for(int s=0;s<24;s++) Bp[s] = *(const bf16x8*)(wrow + s*32);
  }

  int it_col[3], it_c8[3];
#pragma unroll
  for(int j=0;j<3;j++){
    int idx = j*256 + tid;
    it_c8[j] = idx&7;
    int tau = (idx>>3)%12; int nl = idx/96;
    it_col[j] = nl*12 + tau;
  }
  const unsigned short* xbase = xt2 + (size_t)(b*2048 + nh*64)*768;

  uint4 r[3];
#pragma unroll
  for(int j=0;j<3;j++)
    r[j] = *(const uint4*)(xbase + (size_t)it_col[j]*64 + it_c8[j]*8);
#pragma unroll
  for(int j=0;j<3;j++){
    const unsigned short* pr = (const unsigned short*)&r[j];
#pragma unroll
    for(int i=0;i<8;i++) A[0][(it_c8[j]*8+i)*APAD + it_col[j]] = pr[i];
  }
  __syncthreads();

  f32x4 acc = (f32x4){0.f,0.f,0.f,0.f};
  for(int ch=0; ch<8; ch++){
    int cur = ch&1;
    if(ch<7){
      const unsigned short* nb = xbase + (size_t)(ch+1)*8*768;
#pragma unroll
      for(int j=0;j<3;j++)
        r[j] = *(const uint4*)(nb + (size_t)it_col[j]*64 + it_c8[j]*8);
    }
#pragma unroll
    for(int s=0;s<3;s++){
      bf16x8 a = *(const bf16x8*)&A[cur][(wv*16+llo)*APAD + s*32 + lhi*8];
      acc = __builtin_amdgcn_mfma_f32_16x16x32_bf16(a, Bp[ch*3+s], acc, 0,0,0);
    }
    if(ch<7){
#pragma unroll
      for(int j=0;j<3;j++){
        const unsigned short* pr = (const unsigned short*)&r[j];
#pragma unroll
        for(int i=0;i<8;i++) A[cur^1][(it_c8[j]*8+i)*APAD + it_col[j]] = pr[i];
      }
      __syncthreads();
    }
  }

  if(llo<12){
    float bbv = fb[llo];
#pragma unroll
    for(int i=0;i<4;i++){
      int c = wv*16 + lhi*4 + i;
      out[((size_t)b*2048 + c*32 + nh)*12 + llo] = acc[i] + bbv;
    }
  }
}

extern "C" void kernel_launch(void* const* d_in, const int* in_sizes, int n_in,
                              void* d_out, int out_size, void* d_ws, size_t ws_size,
                              hipStream_t stream) {
  (void)n_in; (void)out_size; (void)ws_size;
  const float* x    = (const float*)d_in[0];
  const int*   src  = (const int*)d_in[1];
  const int*   dst  = (const int*)d_in[2];
  const float* W1   = (const float*)d_in[3];
  const float* al1  = (const float*)d_in[4];
  const float* ar1  = (const float*)d_in[5];
  const float* b1   = (const float*)d_in[6];
  const float* W2   = (const float*)d_in[7];
  const float* al2  = (const float*)d_in[8];
  const float* ar2  = (const float*)d_in[9];
  const float* b2   = (const float*)d_in[10];
  const float* ln1w = (const float*)d_in[11];
  const float* ln1b = (const float*)d_in[12];
  const float* ln2w = (const float*)d_in[13];
  const float* ln2b = (const float*)d_in[14];
  const float* tc1w = (const float*)d_in[15];
  const float* tc1b = (const float*)d_in[16];
  const float* ln3w = (const float*)d_in[17];
  const float* ln3b = (const float*)d_in[18];
  const float* tc2w = (const float*)d_in[19];
  const float* tc2b = (const float*)d_in[20];
  const float* fcw  = (const float*)d_in[21];
  const float* fcb  = (const float*)d_in[22];
  int E = in_sizes[1];

  unsigned short* U = (unsigned short*)d_ws;
  unsigned short* xg1 = U + 0;             // [2048][32][64] = 4,194,304
  unsigned short* x1g = U + 4194304;       // [2048][64][64] = 8,388,608
  unsigned short* xg2 = U + 12582912;      // [2048][64][64] = 8,388,608
  unsigned short* x2  = U + 20971520;      // [16384][16][64] = 16,777,216
  unsigned short* xt1 = U + 0;             // 12,582,912 (xg1+x1g dead by conv1)
  unsigned short* xt2 = U + 12582912;      // 12,582,912 (xg2+x2-head dead by conv2)
  unsigned short* wf1 = U + 37748736;      // 10368
  unsigned short* wf2 = wf1 + 10368;       // 10368
  unsigned short* wc1 = wf2 + 10368;       // 20480
  unsigned short* wc2 = wc1 + 20480;       // 4096
  unsigned short* wfc = wc2 + 4096;        // 12288
  float* F = (float*)(wfc + 12288);
  float* el1 = F;                    // 131072
  float* er1 = el1 + 131072;         // 131072
  float* el2 = er1 + 131072;         // 262144
  float* er2 = el2 + 262144;         // 262144
  float2* pg1 = (float2*)(er2 + 262144);   // 64*2048
  float2* pg2 = pg1 + 131072;              // 128*2048
  float2* pr4 = pg2 + 262144;              // 196608*4
  float* mu1  = (float*)(pr4 + 786432);    // 64
  float* inv1 = mu1 + 64;
  float* mu2  = inv1 + 64;                 // 128
  float* inv2 = mu2 + 128;
  float* mu3  = inv2 + 128;                // 96
  float* inv3 = mu3 + 96;
  int* rs     = (int*)(inv3 + 96);   // 2049
  int* csrsrc = rs + 2049;           // E

  // front-end: weight prep + CSR + prepx1 in ONE kernel
  k_setup<<<1031,256,0,stream>>>(dst, src, E, W1,al1,ar1, W2,al2,ar2,
                                 tc1w, tc2w, fcw, x,
                                 wf1, wf2, wc1, wc2, wfc, rs, csrsrc,
                                 xg1, el1, er1);

  // GAT layer 1: fused aggregate+GEMM
  k_gat_fused<32><<<2048,256,0,stream>>>(xg1, el1, er1, rs, csrsrc, wf1, b1, x1g, pg1);
  k_lnfin<<<64,256,0,stream>>>(pg1, mu1, inv1, 0, 8);

  // GAT layer 2: LN1 + gather image + el/er, then fused aggregate+GEMM
  k_prepx2<<<2048,256,0,stream>>>(x1g, mu1, inv1, ln1w, ln1b, wf2, xg2, el2, er2);
  k_gat_fused<64><<<2048,256,0,stream>>>(xg2, el2, er2, rs, csrsrc, wf2, b2, x2, pg2);
  k_lnfin<<<128,256,0,stream>>>(pg2, mu2, inv2, 0, 16);

  // tc1 (5-tap, 16->12), LN2 fused, emits LN3 partials (co-sliced)
  k_convT<16,12,5,true><<<1024,256,0,stream>>>(x2, mu2, inv2, ln2w, ln2b, wc1, tc1b, xt1, pr4);
  k_lnfin<<<96,256,0,stream>>>(pr4, mu3, inv3, 1, 0);

  // tc2 (1x1), LN3 fused
  k_convT<12,12,1,false><<<1024,256,0,stream>>>(xt1, mu3, inv3, ln3w, ln3b, wc2, tc2b, xt2, nullptr);

  // final fc (MFMA)
  k_fcm<<<256,256,0,stream>>>(xt2, wfc, fcb, (float*)d_out);
}

// Round 18
// 157.949 us; speedup vs baseline: 1.1354x; 1.0956x over previous
//
#include <hip/hip_runtime.h>
#include <math.h>

#define NN 2048
#define BB 8
#define HH 2
#define NEG 0.2f
#define EPSL 1e-5f

typedef short bf16x8 __attribute__((ext_vector_type(8)));
typedef float f32x4 __attribute__((ext_vector_type(4)));

__device__ __forceinline__ float wave_reduce_sum(float v){
#pragma unroll
  for (int m = 32; m > 0; m >>= 1) v += __shfl_xor(v, m, 64);
  return v;
}

__device__ __forceinline__ unsigned short f2b(float f){
  union { float f; unsigned u; } v; v.f = f;
  unsigned r = v.u + 0x7FFFu + ((v.u >> 16) & 1u);
  return (unsigned short)(r >> 16);
}
__device__ __forceinline__ float b2f(unsigned short u){
  union { unsigned u; float f; } v; v.u = ((unsigned)u) << 16; return v.f;
}

// vectorized wlr fold: wlr[k][q] = sum_c W[k*128+h*64+c]*av[h*64+c], q=(ar?2:0)+h
__device__ __forceinline__ float fold_dot(const float* __restrict__ W,
                                          const float* __restrict__ av,
                                          int k, int h){
  float s = 0.f;
#pragma unroll
  for(int c4=0;c4<16;c4++){
    float4 w = *(const float4*)&W[k*128 + h*64 + c4*4];
    float4 a = *(const float4*)&av[h*64 + c4*4];
    s += w.x*a.x + w.y*a.y + w.z*a.z + w.w*a.w;
  }
  return s;
}

// ONE front-end kernel, all roles flattened to ~1 load/thread (no rolled serial loops):
//  blocks [0,32)    wf1        (8192 el)
//  blocks [32,64)   wf2        (8192 el)
//  blocks [64,144)  wc1        (20480 el)
//  blocks [144,160) wc2        (4096 el)
//  blocks [160,208) wfc        (12288 el)
//  block  208       wlr folds  (fully unrolled)
//  block  209       CSR build  (int4-batched count+scan+fill in LDS)
//  blocks 210+      prepx1     (1024 blocks)
__global__ __launch_bounds__(256) void k_setup(
  const int* __restrict__ dst, const int* __restrict__ src, int E,
  const float* __restrict__ W1, const float* __restrict__ al1, const float* __restrict__ ar1,
  const float* __restrict__ W2, const float* __restrict__ al2, const float* __restrict__ ar2,
  const float* __restrict__ tc1w, const float* __restrict__ tc2w, const float* __restrict__ fcw,
  const float* __restrict__ x,
  unsigned short* wf1, unsigned short* wf2,
  unsigned short* wc1, unsigned short* wc2, unsigned short* wfc,
  int* row_start, int* csrsrc,
  unsigned short* __restrict__ xg, float* __restrict__ el, float* __restrict__ er)
{
  int blk = blockIdx.x; int tid = threadIdx.x;
  if(blk < 32){ int i = blk*256+tid; int k=i>>7, co=i&127; wf1[co*72+k]=f2b(W1[i]); return; }
  if(blk < 64){ int i = (blk-32)*256+tid; int k=i>>7, co=i&127; wf2[co*72+k]=f2b(W2[i]); return; }
  if(blk < 144){
    int i = (blk-64)*256+tid;  // < 20480
    int co = i/320, kap = i - co*320;
    int kt = kap>>6, ci = kap&63;
    wc1[co*320+kap] = f2b(tc1w[(co*64+ci)*5+kt]);
    return;
  }
  if(blk < 160){ int i = (blk-144)*256+tid; wc2[i]=f2b(tc2w[i]); return; }
  if(blk < 208){
    int i = (blk-160)*256+tid;  // < 12288
    int o = i/768, f = i - o*768;
    wfc[i] = (o<12)? f2b(fcw[o*768+f]) : (unsigned short)0;
    return;
  }
  if(blk == 208){
    int k=tid>>2, q=tid&3, h=q&1;
    wf1[(128+q)*72+k] = f2b(fold_dot(W1, (q>>1)?ar1:al1, k, h));
    wf2[(128+q)*72+k] = f2b(fold_dot(W2, (q>>1)?ar2:al2, k, h));
    return;
  }
  if(blk == 209){
    // CSR: count -> scan -> fill, int4-batched loads to cut serialized latency
    __shared__ int cnt[2048];
    __shared__ int part[256];
    for(int i=tid;i<2048;i+=256) cnt[i]=0;
    __syncthreads();
    int n4 = E>>2;
    const int4* d4 = (const int4*)dst;
    for(int i=tid;i<n4;i+=256){
      int4 v = d4[i];
      atomicAdd(&cnt[v.x],1); atomicAdd(&cnt[v.y],1);
      atomicAdd(&cnt[v.z],1); atomicAdd(&cnt[v.w],1);
    }
    for(int i=n4*4+tid;i<E;i+=256) atomicAdd(&cnt[dst[i]],1);
    __syncthreads();
    int loc[8]; int s=0;
#pragma unroll
    for(int j=0;j<8;j++){ loc[j]=s; s += cnt[tid*8+j]; }
    part[tid]=s; __syncthreads();
    for(int off=1; off<256; off<<=1){
      int v = (tid>=off)? part[tid-off] : 0;
      __syncthreads();
      part[tid] += v;
      __syncthreads();
    }
    int excl = (tid==0)? 0 : part[tid-1];
#pragma unroll
    for(int j=0;j<8;j++){ int v=excl+loc[j]; row_start[tid*8+j]=v; }
    if(tid==255) row_start[2048]=excl+s;
    __syncthreads();
#pragma unroll
    for(int j=0;j<8;j++) cnt[tid*8+j] = row_start[tid*8+j];
    __syncthreads();
    const int4* s4 = (const int4*)src;
    for(int i=tid;i<n4;i+=256){
      int4 dv = d4[i]; int4 sv = s4[i];
      int p0=atomicAdd(&cnt[dv.x],1); csrsrc[p0]=sv.x;
      int p1=atomicAdd(&cnt[dv.y],1); csrsrc[p1]=sv.y;
      int p2=atomicAdd(&cnt[dv.z],1); csrsrc[p2]=sv.z;
      int p3=atomicAdd(&cnt[dv.w],1); csrsrc[p3]=sv.w;
    }
    for(int i=n4*4+tid;i<E;i+=256){
      int p = atomicAdd(&cnt[dst[i]],1);
      csrsrc[p]=src[i];
    }
    return;
  }

  // prepx1 role
  __shared__ __align__(16) unsigned short xs[64*72];
  __shared__ __align__(16) unsigned short wl[16*72];
  int r0 = (blk-210)*64;
  for(int i=tid;i<16*72;i+=256) wl[i]=0;
  __syncthreads();
  {
    int k=tid>>2, q=tid&3, h=q&1;
    wl[q*72+k] = f2b(fold_dot(W1, (q>>1)?ar1:al1, k, h));
  }
  for(int idx=tid; idx<1024; idx+=256){
    int rl=idx>>4, c4=(idx&15)*4;
    int row=r0+rl; int n_=row>>5, rb=row&31, t=rb>>3, b=rb&7;
    float4 v = *(const float4*)&x[(((size_t)b*2048+n_)*4 + t)*64 + c4];
    unsigned p0 = (unsigned)f2b(v.x) | ((unsigned)f2b(v.y)<<16);
    unsigned p1 = (unsigned)f2b(v.z) | ((unsigned)f2b(v.w)<<16);
    uint2 u = make_uint2(p0,p1);
    *(uint2*)&xs[rl*72+c4] = u;
    *(uint2*)&xg[(size_t)row*64 + c4] = u;
  }
  __syncthreads();
  int wv=tid>>6, lane=tid&63, lhi=lane>>4, llo=lane&15;
  f32x4 accE = (f32x4){0.f,0.f,0.f,0.f};
#pragma unroll
  for(int s=0;s<2;s++){
    bf16x8 a = *(const bf16x8*)&xs[(wv*16+llo)*72 + s*32 + lhi*8];
    bf16x8 be = *(const bf16x8*)&wl[llo*72 + s*32 + lhi*8];
    accE = __builtin_amdgcn_mfma_f32_16x16x32_bf16(a, be, accE, 0,0,0);
  }
  if(llo<4){
#pragma unroll
    for(int i=0;i<4;i++){
      int row = r0 + wv*16 + lhi*4 + i; int n_=row>>5, rb=row&31;
      int idx = n_*64 + rb*2 + (llo&1);
      if(llo<2) el[idx]=accE[i]; else er[idx]=accE[i];
    }
  }
}

// prep layer-2 gather image: x1g [n][64][64] raw -> LN1 -> xg2 [n][64][64] bf16
// + el2/er2 [n][rb*2+h] via wlr2. One node per block; mu index g = b*8+t2 (rb=t2*8+b).
__global__ __launch_bounds__(256) void k_prepx2(
  const unsigned short* __restrict__ x1g, const float* __restrict__ mu,
  const float* __restrict__ inv, const float* __restrict__ lnw, const float* __restrict__ lnb,
  const unsigned short* __restrict__ wf,
  unsigned short* __restrict__ xg2, float* __restrict__ el, float* __restrict__ er)
{
  __shared__ __align__(16) unsigned short xs[64*72];
  int n = blockIdx.x; int tid = threadIdx.x;
  for(int idx=tid; idx<1024; idx+=256){
    int rl=idx>>4, c4=(idx&15)*4;
    int t2=rl>>3, b=rl&7; int g=b*8+t2;
    uint2 u = *(const uint2*)&x1g[((size_t)n*64 + rl)*64 + c4];
    float m_=mu[g], iv=inv[g];
    float4 w4 = *(const float4*)&lnw[n*64+c4];
    float4 b4 = *(const float4*)&lnb[n*64+c4];
    float v0=(b2f((unsigned short)(u.x&0xffff))-m_)*iv*w4.x+b4.x;
    float v1=(b2f((unsigned short)(u.x>>16))  -m_)*iv*w4.y+b4.y;
    float v2=(b2f((unsigned short)(u.y&0xffff))-m_)*iv*w4.z+b4.z;
    float v3=(b2f((unsigned short)(u.y>>16))  -m_)*iv*w4.w+b4.w;
    unsigned p0 = (unsigned)f2b(v0)|((unsigned)f2b(v1)<<16);
    unsigned p1 = (unsigned)f2b(v2)|((unsigned)f2b(v3)<<16);
    uint2 o = make_uint2(p0,p1);
    *(uint2*)&xs[rl*72+c4] = o;
    *(uint2*)&xg2[((size_t)n*64+rl)*64 + c4] = o;
  }
  __syncthreads();
  int wv=tid>>6, lane=tid&63, lhi=lane>>4, llo=lane&15;
  f32x4 accE=(f32x4){0.f,0.f,0.f,0.f};
#pragma unroll
  for(int s=0;s<2;s++){
    bf16x8 a = *(const bf16x8*)&xs[(wv*16+llo)*72 + s*32 + lhi*8];
    bf16x8 be = *(const bf16x8*)&wf[(128+llo)*72 + s*32 + lhi*8];
    accE = __builtin_amdgcn_mfma_f32_16x16x32_bf16(a, be, accE, 0,0,0);
  }
  if(llo<4){
#pragma unroll
    for(int i=0;i<4;i++){
      int rb = wv*16 + lhi*4 + i;
      int idx = n*128 + rb*2 + (llo&1);
      if(llo<2) el[idx]=accE[i]; else er[idx]=accE[i];
    }
  }
}

// Fused GAT aggregate: gather INPUT x (64 ch) with per-(row,h) exp weights (linearity:
// out = W*(sum a_j x_j)), normalize, per-block MFMA with W (both heads), bias+relu,
// write output + LN partials. IR = input rows per node (32 layer1, 64 layer2).
template<int IR>
__global__ __launch_bounds__(256) void k_gat_fused(
  const unsigned short* __restrict__ xg, const float* __restrict__ el,
  const float* __restrict__ er, const int* __restrict__ row_start,
  const int* __restrict__ csrsrc, const unsigned short* __restrict__ wf,
  const float* __restrict__ bias, unsigned short* __restrict__ out,
  float2* __restrict__ pg)
{
  constexpr int TPR = 256/IR;     // threads per row (8 or 4)
  constexpr int CPL = 64/TPR;     // channels per lane (8 or 16)
  constexpr int NU  = CPL/8;      // uint4 per lane (1 or 2)
  constexpr int RT2 = IR/32;      // row tiles per wave (1 or 2)
  __shared__ __align__(16) unsigned short aggl[2][IR][72];
  int n = blockIdx.x; int tid = threadIdx.x;
  int beg = row_start[n]; int deg = row_start[n+1]-beg;
  int wv = tid>>6, lane = tid&63, lhi = lane>>4, llo = lane&15;
  int hW = wv>>1;

  // this wave's W_h panel (B-frags), L2-resident prepped image [co][72]
  bf16x8 Bf[4][2];
#pragma unroll
  for(int ct=0;ct<4;ct++)
#pragma unroll
    for(int s=0;s<2;s++)
      Bf[ct][s] = *(const bf16x8*)&wf[(hW*64+ct*16+llo)*72 + s*32 + lhi*8];

  // gather phase: thread owns (row r, channel slice), both heads' weights
  int r = tid/TPR; int dbase = (tid%TPR)*CPL;
  float2 ern = *(const float2*)&er[(size_t)n*(2*IR) + r*2];
  float acc0[CPL], acc1[CPL];
#pragma unroll
  for(int i=0;i<CPL;i++){ acc0[i]=0.f; acc1[i]=0.f; }
  float ss0=0.f, ss1=0.f;
  const unsigned short* xb = xg + (size_t)r*64 + dbase;

  int sn = csrsrc[beg];
  float2 elv = *(const float2*)&el[(size_t)sn*(2*IR) + r*2];
  uint4 cur[NU];
  {
    const unsigned short* fp = xb + (size_t)sn*(IR*64);
#pragma unroll
    for(int u=0;u<NU;u++) cur[u] = *(const uint4*)(fp + u*8);
  }
  for(int j=0;j<deg;j++){
    float2 elv2 = make_float2(0.f,0.f); uint4 nxt[NU];
    if(j+1<deg){
      int sn2 = csrsrc[beg+j+1];
      elv2 = *(const float2*)&el[(size_t)sn2*(2*IR) + r*2];
      const unsigned short* fp2 = xb + (size_t)sn2*(IR*64);
#pragma unroll
      for(int u=0;u<NU;u++) nxt[u] = *(const uint4*)(fp2 + u*8);
    }
    float e0 = elv.x + ern.x; e0 = e0>0.f? e0 : NEG*e0;
    float e1 = elv.y + ern.y; e1 = e1>0.f? e1 : NEG*e1;
    float w0 = __expf(e0), w1 = __expf(e1);
    ss0 += w0; ss1 += w1;
    const unsigned short* pu = (const unsigned short*)cur;
#pragma unroll
    for(int i=0;i<CPL;i++){ float xv = b2f(pu[i]); acc0[i] += w0*xv; acc1[i] += w1*xv; }
    if(j+1<deg){
      elv = elv2;
#pragma unroll
      for(int u=0;u<NU;u++) cur[u] = nxt[u];
    }
  }
  float is0 = 1.f/ss0, is1 = 1.f/ss1;
#pragma unroll
  for(int i=0;i<CPL;i++){
    aggl[0][r][dbase+i] = f2b(acc0[i]*is0);
    aggl[1][r][dbase+i] = f2b(acc1[i]*is1);
  }
  __syncthreads();

  // per-block GEMM: out rows (r, hW) = agg_h[r] * W_h
  f32x4 acc[RT2][4];
#pragma unroll
  for(int rt=0;rt<RT2;rt++)
#pragma unroll
    for(int ct=0;ct<4;ct++) acc[rt][ct]=(f32x4){0.f,0.f,0.f,0.f};
  int rbase = (wv&1)*(IR/2);
#pragma unroll
  for(int rt=0;rt<RT2;rt++){
#pragma unroll
    for(int s=0;s<2;s++){
      bf16x8 a = *(const bf16x8*)&aggl[hW][rbase+rt*16+llo][s*32+lhi*8];
#pragma unroll
      for(int ct=0;ct<4;ct++)
        acc[rt][ct] = __builtin_amdgcn_mfma_f32_16x16x32_bf16(a, Bf[ct][s], acc[rt][ct], 0,0,0);
    }
  }

#pragma unroll
  for(int rt=0;rt<RT2;rt++){
    float bb[4];
#pragma unroll
    for(int ct=0;ct<4;ct++) bb[ct] = bias[hW*64 + ct*16 + llo];
#pragma unroll
    for(int i=0;i<4;i++){
      int ro = rbase + rt*16 + lhi*4 + i;
      int t_new = (ro>>3)*2 + hW; int bq = ro&7;
      size_t off;
      if constexpr (IR==32) off = ((size_t)n*64 + t_new*8 + bq)*64;      // x1g node-major
      else                  off = (((size_t)bq*2048 + n)*16 + t_new)*64; // x2 conv layout
      float ps=0.f, pq=0.f;
#pragma unroll
      for(int ct=0;ct<4;ct++){
        float v = fmaxf(acc[rt][ct][i] + bb[ct], 0.f);
        out[off + ct*16 + llo] = f2b(v);
        ps += v; pq += v*v;
      }
#pragma unroll
      for(int mM=1;mM<=8;mM<<=1){ ps += __shfl_xor(ps,mM,64); pq += __shfl_xor(pq,mM,64); }
      if(llo==0) pg[(size_t)(ro*2+hW)*2048 + n] = make_float2(ps,pq);
    }
  }
}

// finalize LN stats. mode0: pg[r][2048], r=(t*8+b)*2+h; gout = b*TT2+t*2+h
// mode1: pr4[((b*2048+n)*12+to)*4 + wv] (conv, co-sliced partials)
__global__ void k_lnfin(const float2* __restrict__ p, float* __restrict__ mu, float* __restrict__ inv,
                        int mode, int TT2){
  int g = blockIdx.x; int tid = threadIdx.x;
  float s=0.f, q=0.f;
  if(mode==0){
    int base = g*2048;
    for(int i=tid;i<2048;i+=256){ float2 v = p[base + i]; s+=v.x; q+=v.y; }
  } else {
    int b = g/12; int to = g - b*12;
    for(int i=tid;i<8192;i+=256){
      int n_ = i>>2; int wv = i&3;
      float2 v = p[((size_t)(b*2048+n_)*12 + to)*4 + wv];
      s+=v.x; q+=v.y;
    }
  }
  s = wave_reduce_sum(s); q = wave_reduce_sum(q);
  __shared__ float red[8];
  int wid=tid>>6, lane=tid&63;
  if(lane==0){ red[wid]=s; red[4+wid]=q; }
  __syncthreads();
  if(tid==0){
    float S=red[0]+red[1]+red[2]+red[3];
    float Q=red[4]+red[5]+red[6]+red[7];
    float cnt = 131072.f;
    float m = S/cnt; float var = Q/cnt - m*m;
    int gout;
    if(mode==0){ int h=g&1; int b=(g>>1)&7; int t=g>>4; gout = b*TT2 + t*2 + h; }
    else gout = g;
    mu[gout]=m; inv[gout]=rsqrtf(var+EPSL);
  }
}

// Temporal conv as MFMA GEMM (round-14 form). Co-split: wave w owns co [w*16, w*16+16);
// B-panel in regs. Staging: thread (nd, c4) owns all t.
template<int TIN, int TOUT, int KT, bool PSUM>
__global__ __launch_bounds__(256,4) void k_convT(
  const unsigned short* __restrict__ xin,
  const float* __restrict__ mu, const float* __restrict__ inv,
  const float* __restrict__ lnw, const float* __restrict__ lnb,
  const unsigned short* __restrict__ wcg,   // [64][KT*64] bf16
  const float* __restrict__ bias,
  unsigned short* __restrict__ y, float2* __restrict__ pr4)
{
  constexpr int K = KT*64;
  constexpr int KSTEPS = K/32;
  constexpr int XPAD = 72;
  constexpr int XN = TIN*XPAD + 8;
  constexpr int NODES = 16;
  constexpr int RT = NODES*TOUT/16;
  __shared__ __align__(16) unsigned short xs[NODES*XN];
  int tid = threadIdx.x;
  int bn0 = blockIdx.x*NODES;
  int r0 = bn0*TOUT;
  int wv_ = tid>>6, lane = tid&63, lhi = lane>>4, llo = lane&15;

  bf16x8 bB[KSTEPS];
  {
    const unsigned short* wrow = wcg + (wv_*16+llo)*K;
#pragma unroll
    for(int s=0;s<KSTEPS;s++) bB[s] = *(const bf16x8*)(wrow + s*32 + lhi*8);
  }

  {
    int nd = tid>>4; int c4 = (tid&15)*4;
    int bn = bn0+nd; int b = bn0>>11; int n_ = bn&2047;
    float4 w4 = *(const float4*)&lnw[n_*64+c4];
    float4 b4 = *(const float4*)&lnb[n_*64+c4];
    const unsigned short* xp = xin + (size_t)bn*TIN*64 + c4;
    unsigned short* p0 = &xs[nd*XN + c4];
#pragma unroll
    for(int t=0;t<TIN;t++){
      uint2 u = *(const uint2*)(xp + t*64);
      float m_ = mu[b*TIN+t], iv = inv[b*TIN+t];
      float iw0 = iv*w4.x, iw1 = iv*w4.y, iw2 = iv*w4.z, iw3 = iv*w4.w;
      unsigned short* p = p0 + t*XPAD;
      p[0]=f2b((b2f((unsigned short)(u.x&0xffff))-m_)*iw0+b4.x);
      p[1]=f2b((b2f((unsigned short)(u.x>>16))  -m_)*iw1+b4.y);
      p[2]=f2b((b2f((unsigned short)(u.y&0xffff))-m_)*iw2+b4.z);
      p[3]=f2b((b2f((unsigned short)(u.y>>16))  -m_)*iw3+b4.w);
    }
  }
  __syncthreads();

  f32x4 acc[RT];
#pragma unroll
  for(int rt=0;rt<RT;rt++) acc[rt] = (f32x4){0.f,0.f,0.f,0.f};

#pragma unroll
  for(int rt=0; rt<RT; rt++){
    int rr = rt*16 + llo;
    int nd = rr/TOUT; int to = rr - nd*TOUT;
    const unsigned short* ap = &xs[nd*XN + to*XPAD];
#pragma unroll
    for(int s=0;s<KSTEPS;s++){
      int ktap = s>>1; int cib = ((s&1)<<5) + lhi*8;
      bf16x8 a = *(const bf16x8*)(ap + ktap*XPAD + cib);
      acc[rt] = __builtin_amdgcn_mfma_f32_16x16x32_bf16(a, bB[s], acc[rt], 0,0,0);
    }
  }

  float bb = bias[wv_*16 + llo];
#pragma unroll
  for(int rt=0; rt<RT; rt++){
    float vs[4];
#pragma unroll
    for(int i=0;i<4;i++) vs[i] = acc[rt][i] + bb;
#pragma unroll
    for(int i=0;i<4;i++)
      y[(size_t)(r0 + rt*16 + lhi*4 + i)*64 + wv_*16 + llo] = f2b(vs[i]);
    if constexpr (PSUM){
#pragma unroll
      for(int i=0;i<4;i++){
        float s = vs[i], q = vs[i]*vs[i];
#pragma unroll
        for(int mM=1;mM<=8;mM<<=1){ s += __shfl_xor(s,mM,64); q += __shfl_xor(q,mM,64); }
        if(llo==0) pr4[(size_t)(r0 + rt*16 + lhi*4 + i)*4 + wv_] = make_float2(s,q);
      }
    }
  }
}

// final fc as MFMA GEMM. Block=(b,nh). M=64 (c, split 16/wave), N=12(pad16, o), K=768.
__global__ __launch_bounds__(256) void k_fcm(const unsigned short* __restrict__ xt2,
  const unsigned short* __restrict__ wfc, const float* __restrict__ fb, float* __restrict__ out)
{
  constexpr int APAD = 102;
  __shared__ unsigned short A[2][64*APAD];
  int tid = threadIdx.x;
  int b = blockIdx.x>>5, nh = blockIdx.x&31;
  int wv = tid>>6, lane = tid&63, lhi = lane>>4, llo = lane&15;

  bf16x8 Bp[24];
  {
    const unsigned short* wrow = wfc + llo*768 + lhi*8;
#pragma unroll
    for(int s=0;s<24;s++) Bp[s] = *(const bf16x8*)(wrow + s*32);
  }

  int it_col[3], it_c8[3];
#pragma unroll
  for(int j=0;j<3;j++){
    int idx = j*256 + tid;
    it_c8[j] = idx&7;
    int tau = (idx>>3)%12; int nl = idx/96;
    it_col[j] = nl*12 + tau;
  }
  const unsigned short* xbase = xt2 + (size_t)(b*2048 + nh*64)*768;

  uint4 r[3];
#pragma unroll
  for(int j=0;j<3;j++)
    r[j] = *(const uint4*)(xbase + (size_t)it_col[j]*64 + it_c8[j]*8);
#pragma unroll
  for(int j=0;j<3;j++){
    const unsigned short* pr = (const unsigned short*)&r[j];
#pragma unroll
    for(int i=0;i<8;i++) A[0][(it_c8[j]*8+i)*APAD + it_col[j]] = pr[i];
  }
  __syncthreads();

  f32x4 acc = (f32x4){0.f,0.f,0.f,0.f};
  for(int ch=0; ch<8; ch++){
    int cur = ch&1;
    if(ch<7){
      const unsigned short* nb = xbase + (size_t)(ch+1)*8*768;
#pragma unroll
      for(int j=0;j<3;j++)
        r[j] = *(const uint4*)(nb + (size_t)it_col[j]*64 + it_c8[j]*8);
    }
#pragma unroll
    for(int s=0;s<3;s++){
      bf16x8 a = *(const bf16x8*)&A[cur][(wv*16+llo)*APAD + s*32 + lhi*8];
      acc = __builtin_amdgcn_mfma_f32_16x16x32_bf16(a, Bp[ch*3+s], acc, 0,0,0);
    }
    if(ch<7){
#pragma unroll
      for(int j=0;j<3;j++){
        const unsigned short* pr = (const unsigned short*)&r[j];
#pragma unroll
        for(int i=0;i<8;i++) A[cur^1][(it_c8[j]*8+i)*APAD + it_col[j]] = pr[i];
      }
      __syncthreads();
    }
  }

  if(llo<12){
    float bbv = fb[llo];
#pragma unroll
    for(int i=0;i<4;i++){
      int c = wv*16 + lhi*4 + i;
      out[((size_t)b*2048 + c*32 + nh)*12 + llo] = acc[i] + bbv;
    }
  }
}

extern "C" void kernel_launch(void* const* d_in, const int* in_sizes, int n_in,
                              void* d_out, int out_size, void* d_ws, size_t ws_size,
                              hipStream_t stream) {
  (void)n_in; (void)out_size; (void)ws_size;
  const float* x    = (const float*)d_in[0];
  const int*   src  = (const int*)d_in[1];
  const int*   dst  = (const int*)d_in[2];
  const float* W1   = (const float*)d_in[3];
  const float* al1  = (const float*)d_in[4];
  const float* ar1  = (const float*)d_in[5];
  const float* b1   = (const float*)d_in[6];
  const float* W2   = (const float*)d_in[7];
  const float* al2  = (const float*)d_in[8];
  const float* ar2  = (const float*)d_in[9];
  const float* b2   = (const float*)d_in[10];
  const float* ln1w = (const float*)d_in[11];
  const float* ln1b = (const float*)d_in[12];
  const float* ln2w = (const float*)d_in[13];
  const float* ln2b = (const float*)d_in[14];
  const float* tc1w = (const float*)d_in[15];
  const float* tc1b = (const float*)d_in[16];
  const float* ln3w = (const float*)d_in[17];
  const float* ln3b = (const float*)d_in[18];
  const float* tc2w = (const float*)d_in[19];
  const float* tc2b = (const float*)d_in[20];
  const float* fcw  = (const float*)d_in[21];
  const float* fcb  = (const float*)d_in[22];
  int E = in_sizes[1];

  unsigned short* U = (unsigned short*)d_ws;
  unsigned short* xg1 = U + 0;             // [2048][32][64] = 4,194,304
  unsigned short* x1g = U + 4194304;       // [2048][64][64] = 8,388,608
  unsigned short* xg2 = U + 12582912;      // [2048][64][64] = 8,388,608
  unsigned short* x2  = U + 20971520;      // [16384][16][64] = 16,777,216
  unsigned short* xt1 = U + 0;             // 12,582,912 (xg1+x1g dead by conv1)
  unsigned short* xt2 = U + 12582912;      // 12,582,912 (xg2+x2-head dead by conv2)
  unsigned short* wf1 = U + 37748736;      // 10368
  unsigned short* wf2 = wf1 + 10368;       // 10368
  unsigned short* wc1 = wf2 + 10368;       // 20480
  unsigned short* wc2 = wc1 + 20480;       // 4096
  unsigned short* wfc = wc2 + 4096;        // 12288
  float* F = (float*)(wfc + 12288);
  float* el1 = F;                    // 131072
  float* er1 = el1 + 131072;         // 131072
  float* el2 = er1 + 131072;         // 262144
  float* er2 = el2 + 262144;         // 262144
  float2* pg1 = (float2*)(er2 + 262144);   // 64*2048
  float2* pg2 = pg1 + 131072;              // 128*2048
  float2* pr4 = pg2 + 262144;              // 196608*4
  float* mu1  = (float*)(pr4 + 786432);    // 64
  float* inv1 = mu1 + 64;
  float* mu2  = inv1 + 64;                 // 128
  float* inv2 = mu2 + 128;
  float* mu3  = inv2 + 128;                // 96
  float* inv3 = mu3 + 96;
  int* rs     = (int*)(inv3 + 96);   // 2049
  int* csrsrc = rs + 2049;           // E

  // front-end: weight prep (flattened) + CSR (int4-batched) + prepx1 in ONE kernel
  k_setup<<<1234,256,0,stream>>>(dst, src, E, W1,al1,ar1, W2,al2,ar2,
                                 tc1w, tc2w, fcw, x,
                                 wf1, wf2, wc1, wc2, wfc, rs, csrsrc,
                                 xg1, el1, er1);

  // GAT layer 1: fused aggregate+GEMM
  k_gat_fused<32><<<2048,256,0,stream>>>(xg1, el1, er1, rs, csrsrc, wf1, b1, x1g, pg1);
  k_lnfin<<<64,256,0,stream>>>(pg1, mu1, inv1, 0, 8);

  // GAT layer 2: LN1 + gather image + el/er, then fused aggregate+GEMM
  k_prepx2<<<2048,256,0,stream>>>(x1g, mu1, inv1, ln1w, ln1b, wf2, xg2, el2, er2);
  k_gat_fused<64><<<2048,256,0,stream>>>(xg2, el2, er2, rs, csrsrc, wf2, b2, x2, pg2);
  k_lnfin<<<128,256,0,stream>>>(pg2, mu2, inv2, 0, 16);

  // tc1 (5-tap, 16->12), LN2 fused, emits LN3 partials (co-sliced)
  k_convT<16,12,5,true><<<1024,256,0,stream>>>(x2, mu2, inv2, ln2w, ln2b, wc1, tc1b, xt1, pr4);
  k_lnfin<<<96,256,0,stream>>>(pr4, mu3, inv3, 1, 0);

  // tc2 (1x1), LN3 fused
  k_convT<12,12,1,false><<<1024,256,0,stream>>>(xt1, mu3, inv3, ln3w, ln3b, wc2, tc2b, xt2, nullptr);

  // final fc (MFMA)
  k_fcm<<<256,256,0,stream>>>(xt2, wfc, fcb, (float*)d_out);
}